// Round 4
// baseline (2550.475 us; speedup 1.0000x reference)
//
#include <hip/hip_runtime.h>
#include <cstdint>

#define Dm 1024
#define Tm 1024
#define Bm 2
#define Lm 8
#define FFm 4096
#define Vm 50257
#define Mm (Bm * Tm)
#define VPAD 50304  // 393*128, zero-padded bf16 tok_emb rows

typedef __bf16 bf16x8 __attribute__((ext_vector_type(8)));
typedef float f32x4 __attribute__((ext_vector_type(4)));
typedef unsigned short u16;
typedef unsigned int u32;
typedef u16 u16x8 __attribute__((ext_vector_type(8)));
typedef u16 u16x4 __attribute__((ext_vector_type(4)));

__device__ __forceinline__ u16 f2bf(float f) {
  u32 u = __float_as_uint(f);
  u += 0x7FFFu + ((u >> 16) & 1u);
  return (u16)(u >> 16);
}
__device__ __forceinline__ float bf2f(u16 u) {
  return __uint_as_float((u32)u << 16);
}
__device__ __forceinline__ u32 packbf(float lo, float hi) {
  return (u32)f2bf(lo) | ((u32)f2bf(hi) << 16);
}

// async global->LDS, 16B per lane. LDS dest: wave-uniform base + lane*16.
__device__ __forceinline__ void gload16(const u16* g, u16* l) {
  __builtin_amdgcn_global_load_lds(
      (const __attribute__((address_space(1))) void*)g,
      (__attribute__((address_space(3))) void*)l, 16, 0, 0);
}

// ---------------- embedding ----------------
__global__ __launch_bounds__(256) void embed_k(
    const int* __restrict__ idx, const float* __restrict__ tok,
    const float* __restrict__ pos, float* __restrict__ x) {
  int m = blockIdx.x, t = threadIdx.x;
  int id = idx[m];
  int tt = m & (Tm - 1);
  float4 a = *(const float4*)(tok + (size_t)id * Dm + t * 4);
  float4 p = *(const float4*)(pos + (size_t)tt * Dm + t * 4);
  float4 o;
  o.x = a.x + p.x; o.y = a.y + p.y; o.z = a.z + p.z; o.w = a.w + p.w;
  *(float4*)(x + (size_t)m * Dm + t * 4) = o;
}

// ---------------- weight conversion fp32 -> bf16 ----------------
__global__ __launch_bounds__(256) void conv_k(const float* __restrict__ s,
                                              u16* __restrict__ d,
                                              long long nsrc, long long ntot) {
  long long i = ((long long)blockIdx.x * 256 + threadIdx.x) * 8;
  if (i >= ntot) return;
  u16x8 r = {0, 0, 0, 0, 0, 0, 0, 0};
  if (i < nsrc) {
    float4 a = *(const float4*)(s + i);
    float4 b = *(const float4*)(s + i + 4);
    r[0] = f2bf(a.x); r[1] = f2bf(a.y); r[2] = f2bf(a.z); r[3] = f2bf(a.w);
    r[4] = f2bf(b.x); r[5] = f2bf(b.y); r[6] = f2bf(b.z); r[7] = f2bf(b.w);
  }
  *(u16x8*)(d + i) = r;
}

#define R0 (3 * Dm * Dm)
#define R1 (Dm * Dm)
#define R2 (FFm * Dm)
#define R3 (Dm * FFm)
__global__ __launch_bounds__(256) void convw_k(
    const float* __restrict__ s0, const float* __restrict__ s1,
    const float* __restrict__ s2, const float* __restrict__ s3,
    u16* __restrict__ d) {
  size_t i = ((size_t)blockIdx.x * 256 + threadIdx.x) * 8;
  const float* s;
  size_t o;
  if (i < R0) { s = s0; o = i; }
  else if (i < (size_t)R0 + R1) { s = s1; o = i - R0; }
  else if (i < (size_t)R0 + R1 + R2) { s = s2; o = i - R0 - R1; }
  else { s = s3; o = i - R0 - R1 - R2; }
  float4 a = *(const float4*)(s + o);
  float4 b = *(const float4*)(s + o + 4);
  u16x8 r;
  r[0] = f2bf(a.x); r[1] = f2bf(a.y); r[2] = f2bf(a.z); r[3] = f2bf(a.w);
  r[4] = f2bf(b.x); r[5] = f2bf(b.y); r[6] = f2bf(b.z); r[7] = f2bf(b.w);
  *(u16x8*)(d + i) = r;
}

// ---------------- layernorm (fp32 in, bf16 out) ----------------
__global__ __launch_bounds__(256) void ln_k(const float* __restrict__ x,
                                            const float* __restrict__ w,
                                            const float* __restrict__ b,
                                            u16* __restrict__ out) {
  __shared__ float red[4];
  int row = blockIdx.x, t = threadIdx.x;
  float4 v = *(const float4*)(x + (size_t)row * Dm + t * 4);
  float s = v.x + v.y + v.z + v.w;
#pragma unroll
  for (int mm = 1; mm < 64; mm <<= 1) s += __shfl_xor(s, mm);
  if ((t & 63) == 0) red[t >> 6] = s;
  __syncthreads();
  float mu = (red[0] + red[1] + red[2] + red[3]) * (1.0f / Dm);
  __syncthreads();
  float dx = v.x - mu, dy = v.y - mu, dz = v.z - mu, dw = v.w - mu;
  float sq = dx * dx + dy * dy + dz * dz + dw * dw;
#pragma unroll
  for (int mm = 1; mm < 64; mm <<= 1) sq += __shfl_xor(sq, mm);
  if ((t & 63) == 0) red[t >> 6] = sq;
  __syncthreads();
  float var = (red[0] + red[1] + red[2] + red[3]) * (1.0f / Dm);
  float rs = rsqrtf(var + 1e-5f);
  float4 wv = *(const float4*)(w + t * 4);
  float4 bv = *(const float4*)(b + t * 4);
  u16x4 o;
  o[0] = f2bf(dx * rs * wv.x + bv.x);
  o[1] = f2bf(dy * rs * wv.y + bv.y);
  o[2] = f2bf(dz * rs * wv.z + bv.z);
  o[3] = f2bf(dw * rs * wv.w + bv.w);
  *(u16x4*)(out + (size_t)row * Dm + t * 4) = o;
}

// ---------------- GEMM: C[M,·] = A[M,K] @ W[·,K]^T ----------------
// 128x128 tile, 4 waves, BK=32, mfma 16x16x32 bf16.
// Double-buffered (T3 2-phase): STAGE(next) -> ds_read(cur)+MFMA -> barrier.
// global_load_lds width-16, source-chunk XOR swizzle (2-way = free).
__global__ __launch_bounds__(256) void gemm_k(
    const u16* __restrict__ A, const u16* __restrict__ W,
    const float* __restrict__ bias, const float* __restrict__ res,
    float* __restrict__ Cf, u16* __restrict__ Cb, int ldc, int nstore, int K,
    int gelu, int mblks, int nblks) {
  __shared__ __align__(16) u16 As[2][4096];
  __shared__ __align__(16) u16 Ws[2][4096];
  int id = blockIdx.x;
  int c = id & 7, m2 = id >> 3;
  int bx = m2 % mblks;
  int by = (m2 / mblks) * 8 + c;
  if (by >= nblks) return;
  int m0 = bx << 7, n0 = by << 7;
  int t = threadIdx.x;
  int wave = t >> 6, lane = t & 63;
  int wm = (wave & 1) << 6, wn = (wave >> 1) << 6;
  int lr = lane & 15, cq = lane >> 4;

  f32x4 acc[4][4] = {};

  int ch0 = wave * 64 + lane;
  int ch1 = 256 + ch0;
  int r0 = ch0 >> 2, c0 = (ch0 & 3) ^ ((r0 >> 1) & 3);
  int r1 = ch1 >> 2, c1 = (ch1 & 3) ^ ((r1 >> 1) & 3);
  const u16* gA0 = A + (size_t)(m0 + r0) * K + c0 * 8;
  const u16* gA1 = A + (size_t)(m0 + r1) * K + c1 * 8;
  const u16* gW0 = W + (size_t)(n0 + r0) * K + c0 * 8;
  const u16* gW1 = W + (size_t)(n0 + r1) * K + c1 * 8;

  int nst = K >> 5;
  // prologue: stage tile 0 into buf 0
  gload16(gA0, &As[0][wave * 512]);
  gload16(gA1, &As[0][2048 + wave * 512]);
  gload16(gW0, &Ws[0][wave * 512]);
  gload16(gW1, &Ws[0][2048 + wave * 512]);
  __syncthreads();

  for (int i = 0; i < nst; ++i) {
    int cur = i & 1;
    if (i + 1 < nst) {
      int ko = (i + 1) << 5;
      gload16(gA0 + ko, &As[cur ^ 1][wave * 512]);
      gload16(gA1 + ko, &As[cur ^ 1][2048 + wave * 512]);
      gload16(gW0 + ko, &Ws[cur ^ 1][wave * 512]);
      gload16(gW1 + ko, &Ws[cur ^ 1][2048 + wave * 512]);
    }
    bf16x8 af[4], bf[4];
#pragma unroll
    for (int mi = 0; mi < 4; ++mi) {
      int rr = wm + mi * 16 + lr;
      af[mi] =
          *(const bf16x8*)&As[cur][rr * 32 + ((cq ^ ((rr >> 1) & 3)) << 3)];
    }
#pragma unroll
    for (int ni = 0; ni < 4; ++ni) {
      int rr = wn + ni * 16 + lr;
      bf[ni] =
          *(const bf16x8*)&Ws[cur][rr * 32 + ((cq ^ ((rr >> 1) & 3)) << 3)];
    }
#pragma unroll
    for (int mi = 0; mi < 4; ++mi)
#pragma unroll
      for (int ni = 0; ni < 4; ++ni)
        acc[mi][ni] = __builtin_amdgcn_mfma_f32_16x16x32_bf16(
            af[mi], bf[ni], acc[mi][ni], 0, 0, 0);
    __syncthreads();
  }

  // epilogue: C/D layout col=lane&15, row=(lane>>4)*4+reg [m89]
  int orow = cq << 2, ocol = lr;
#pragma unroll
  for (int mi = 0; mi < 4; ++mi) {
#pragma unroll
    for (int ni = 0; ni < 4; ++ni) {
      int gm = m0 + wm + mi * 16 + orow;
      int gn = n0 + wn + ni * 16 + ocol;
      if (gn < nstore) {
        float bv = bias ? bias[gn] : 0.f;
#pragma unroll
        for (int j = 0; j < 4; ++j) {
          float o = acc[mi][ni][j] + bv;
          if (gelu) o = 0.5f * o * (1.0f + erff(o * 0.70710678118654752f));
          if (res) o += res[(size_t)(gm + j) * ldc + gn];
          if (Cb) Cb[(size_t)(gm + j) * ldc + gn] = f2bf(o);
          else Cf[(size_t)(gm + j) * ldc + gn] = o;
        }
      }
    }
  }
}

// ---------------- V transpose: qkv V-part -> vt[bh][d][t] ----------------
__global__ __launch_bounds__(256) void vtr_k(const u16* __restrict__ qkv,
                                             u16* __restrict__ vt) {
  __shared__ u16 T[64 * 68];
  int bh = blockIdx.y;
  int b = bh >> 4, h = bh & 15;
  int t0 = blockIdx.x << 6;
  int tid = threadIdx.x;
  int r = tid >> 2, q4 = tid & 3;
  const u16* src = qkv + (size_t)(b * Tm + t0 + r) * 3072 + 2048 + h * 64 +
                   q4 * 16;
  *(u16x8*)&T[r * 68 + q4 * 16] = *(const u16x8*)src;
  *(u16x8*)&T[r * 68 + q4 * 16 + 8] = *(const u16x8*)(src + 8);
  __syncthreads();
  int dr = tid >> 2, kq = tid & 3;
  u16x8 o0, o1;
#pragma unroll
  for (int u = 0; u < 8; ++u) o0[u] = T[(kq * 16 + u) * 68 + dr];
#pragma unroll
  for (int u = 0; u < 8; ++u) o1[u] = T[(kq * 16 + 8 + u) * 68 + dr];
  u16* dst = vt + ((size_t)bh * 64 + dr) * 1024 + t0 + kq * 16;
  *(u16x8*)dst = o0;
  *(u16x8*)(dst + 8) = o1;
}

// ---------------- MFMA flash attention v2 ----------------
// Swapped QK^T: s = mfma(K,Q) -> S^T, q = lane&15 -> softmax is 16 in-lane
// values + 2 shfl_xor. P stays in-register; 16-shuffle redistribution into
// the PV A-operand layout. V pre-transposed globally (vt), staged linearly.
// K/V double-buffered; 1 barrier per tile.
__global__ __launch_bounds__(256) void attn_k(const u16* __restrict__ qkv,
                                              const u16* __restrict__ vt,
                                              u16* __restrict__ y) {
  __shared__ __align__(16) u16 Ks[2][4096];
  __shared__ __align__(16) u16 Vs[2][4096];
  int qt = gridDim.x - 1 - blockIdx.x;  // big blocks first
  int q0 = qt << 6;
  int bh = blockIdx.y;
  int b = bh >> 4, h = bh & 15;
  int t = threadIdx.x, wave = t >> 6, lane = t & 63;
  int lr = lane & 15, cq = lane >> 4;

  // Q fragments (B-operand), pre-scaled by 1/8 (exact in bf16)
  bf16x8 qf[2];
  {
    size_t base = (size_t)(b * Tm + q0 + wave * 16 + lr) * 3072 + h * 64;
#pragma unroll
    for (int ks = 0; ks < 2; ++ks) {
      u16x8 qa = *(const u16x8*)(qkv + base + ks * 32 + cq * 8);
#pragma unroll
      for (int u = 0; u < 8; ++u) qa[u] = f2bf(bf2f(qa[u]) * 0.125f);
      qf[ks] = *(bf16x8*)&qa;
    }
  }

  f32x4 accO[4] = {};
  float m_run = -1e30f, l_run = 0.f;  // per lane, stats for q = lr

  // staging addresses
  int ch0 = wave * 64 + lane, ch1 = 256 + ch0;
  int kr0 = ch0 >> 3, kc0 = ((ch0 & 7) ^ (kr0 & 7)) << 3;
  int kr1 = ch1 >> 3, kc1 = ((ch1 & 7) ^ (kr1 & 7)) << 3;
  const u16* kbase = qkv + (size_t)b * Tm * 3072 + 1024 + h * 64;
  const u16* vbase = vt + (size_t)bh * 64 * 1024;

  {
    // prologue: stage tile 0 into buf 0
    gload16(kbase + (size_t)kr0 * 3072 + kc0, &Ks[0][wave * 512]);
    gload16(kbase + (size_t)kr1 * 3072 + kc1, &Ks[0][2048 + wave * 512]);
    gload16(vbase + (size_t)kr0 * 1024 + kc0, &Vs[0][wave * 512]);
    gload16(vbase + (size_t)kr1 * 1024 + kc1, &Vs[0][2048 + wave * 512]);
  }
  __syncthreads();

  for (int tk = 0; tk <= qt; ++tk) {
    int cur = tk & 1;
    if (tk < qt) {
      int kb0 = (tk + 1) << 6;
      gload16(kbase + (size_t)(kb0 + kr0) * 3072 + kc0,
              &Ks[cur ^ 1][wave * 512]);
      gload16(kbase + (size_t)(kb0 + kr1) * 3072 + kc1,
              &Ks[cur ^ 1][2048 + wave * 512]);
      gload16(vbase + (size_t)kr0 * 1024 + kb0 + kc0,
              &Vs[cur ^ 1][wave * 512]);
      gload16(vbase + (size_t)kr1 * 1024 + kb0 + kc1,
              &Vs[cur ^ 1][2048 + wave * 512]);
    }

    // S^T = K Q^T : s[ni][r] = S[kk = ni*16 + cq*4 + r][q = lr]
    f32x4 s[4] = {};
    __builtin_amdgcn_s_setprio(1);
#pragma unroll
    for (int ks = 0; ks < 2; ++ks)
#pragma unroll
      for (int ni = 0; ni < 4; ++ni) {
        int rk = ni * 16 + lr;
        int ck = ks * 4 + cq;
        bf16x8 kf = *(const bf16x8*)&Ks[cur][rk * 64 + ((ck ^ (rk & 7)) << 3)];
        s[ni] = __builtin_amdgcn_mfma_f32_16x16x32_bf16(kf, qf[ks], s[ni],
                                                        0, 0, 0);
      }
    __builtin_amdgcn_s_setprio(0);

    if (tk == qt) {  // causal mask, last tile only
      int kb0 = tk << 6;
      int qa = q0 + wave * 16 + lr;
#pragma unroll
      for (int ni = 0; ni < 4; ++ni)
#pragma unroll
        for (int r = 0; r < 4; ++r)
          if (kb0 + ni * 16 + cq * 4 + r > qa) s[ni][r] = -1e30f;
    }

    // online softmax: 16 in-lane values (all for q = lr)
    float mx = fmaxf(fmaxf(s[0][0], s[0][1]), fmaxf(s[0][2], s[0][3]));
#pragma unroll
    for (int ni = 1; ni < 4; ++ni)
      mx = fmaxf(mx, fmaxf(fmaxf(s[ni][0], s[ni][1]),
                           fmaxf(s[ni][2], s[ni][3])));
    mx = fmaxf(mx, __shfl_xor(mx, 16));
    mx = fmaxf(mx, __shfl_xor(mx, 32));
    float mn = fmaxf(m_run, mx);
    float alpha = __expf(m_run - mn);
    m_run = mn;
    float ls = 0.f;
    u32 packed[4][2];
#pragma unroll
    for (int ni = 0; ni < 4; ++ni) {
      float p0 = __expf(s[ni][0] - mn), p1 = __expf(s[ni][1] - mn);
      float p2 = __expf(s[ni][2] - mn), p3 = __expf(s[ni][3] - mn);
      ls += (p0 + p1) + (p2 + p3);
      packed[ni][0] = packbf(p0, p1);
      packed[ni][1] = packbf(p2, p3);
    }
    ls += __shfl_xor(ls, 16);
    ls += __shfl_xor(ls, 32);
    l_run = l_run * alpha + ls;

    // rescale O by alpha of q = cq*4+j (stats live at lane lr = q)
#pragma unroll
    for (int j = 0; j < 4; ++j) {
      float a = __shfl(alpha, (cq << 2) + j);
#pragma unroll
      for (int di = 0; di < 4; ++di) accO[di][j] *= a;
    }

    // P redistribution: target lane (lr,cq) needs P[q=lr][k=ks2*32+cq*8+e]
    // source: packed[2*ks2 + (cq>>1)][w&1] at lane lr + 16*((cq&1)*2+(w>>1))
    bf16x8 pf[2];
#pragma unroll
    for (int ks2 = 0; ks2 < 2; ++ks2) {
      union { u32 w[4]; bf16x8 v; } pu;
#pragma unroll
      for (int w = 0; w < 4; ++w) {
        int src = lr + 16 * (((cq & 1) << 1) + (w >> 1));
        int a = __shfl((int)packed[2 * ks2][w & 1], src);
        int bb = __shfl((int)packed[2 * ks2 + 1][w & 1], src);
        pu.w[w] = (cq >> 1) ? (u32)bb : (u32)a;
      }
      pf[ks2] = pu.v;
    }

    // O += P V : accO[di] = O[q = cq*4+j][d = di*16+lr]
    __builtin_amdgcn_s_setprio(1);
#pragma unroll
    for (int ks2 = 0; ks2 < 2; ++ks2)
#pragma unroll
      for (int di = 0; di < 4; ++di) {
        int rv = di * 16 + lr;
        int ck = ks2 * 4 + cq;
        bf16x8 vf = *(const bf16x8*)&Vs[cur][rv * 64 + ((ck ^ (rv & 7)) << 3)];
        accO[di] = __builtin_amdgcn_mfma_f32_16x16x32_bf16(pf[ks2], vf,
                                                           accO[di], 0, 0, 0);
      }
    __builtin_amdgcn_s_setprio(0);
    __syncthreads();
  }

  float iv = 1.0f / l_run;
  int qrow = q0 + wave * 16 + (cq << 2);
#pragma unroll
  for (int j = 0; j < 4; ++j) {
    float ivj = __shfl(iv, (cq << 2) + j);
    size_t row = (size_t)(b * Tm + qrow + j) * Dm + h * 64;
#pragma unroll
    for (int di = 0; di < 4; ++di)
      y[row + di * 16 + lr] = f2bf(accO[di][j] * ivj);
  }
}

// ---------------- host ----------------
#define WELEMS ((size_t)(R0 + R1 + R2 + R3))  // 12Mi elems per layer

static inline void launch_gemm(const u16* A, const u16* W, const float* bias,
                               const float* res, float* Cf, u16* Cb, int ldc,
                               int nstore, int K, int gelu, int mblks,
                               int nblks, hipStream_t stream) {
  int gx = 8 * mblks * ((nblks + 7) / 8);
  gemm_k<<<gx, 256, 0, stream>>>(A, W, bias, res, Cf, Cb, ldc, nstore, K,
                                 gelu, mblks, nblks);
}

extern "C" void kernel_launch(void* const* d_in, const int* in_sizes, int n_in,
                              void* d_out, int out_size, void* d_ws,
                              size_t ws_size, hipStream_t stream) {
  const int* idx = (const int*)d_in[0];
  const float* tok = (const float*)d_in[1];
  const float* pos = (const float*)d_in[2];
  const float* ln1w = (const float*)d_in[3];
  const float* ln1b = (const float*)d_in[4];
  const float* qkvw = (const float*)d_in[5];
  const float* qkvb = (const float*)d_in[6];
  const float* projw = (const float*)d_in[7];
  const float* projb = (const float*)d_in[8];
  const float* ln2w = (const float*)d_in[9];
  const float* ln2b = (const float*)d_in[10];
  const float* fc1w = (const float*)d_in[11];
  const float* fc1b = (const float*)d_in[12];
  const float* fc2w = (const float*)d_in[13];
  const float* fc2b = (const float*)d_in[14];
  const float* lnfw = (const float*)d_in[15];
  const float* lnfb = (const float*)d_in[16];
  float* out = (float*)d_out;

  // ws layout
  char* w = (char*)d_ws;
  float* x = (float*)w;  w += (size_t)Mm * Dm * 4;   // 8 MB fp32 residual
  u16* h = (u16*)w;      w += (size_t)Mm * Dm * 2;   // 4 MB LN-out / attn-out
  u16* big = (u16*)w;    w += (size_t)Mm * FFm * 2;  // 16 MB qkv/ff union
  u16* vtG = (u16*)w;    w += (size_t)Bm * 16 * 64 * Tm * 2;  // 4 MB V^T
  u16* wbuf = (u16*)w;   w += WELEMS * 2;            // 24 MB layer weights
  u16* tokbf = (u16*)w;
  size_t need_full = (size_t)(w - (char*)d_ws) + (size_t)VPAD * Dm * 2;
  bool full = ws_size >= need_full;

  embed_k<<<Mm, 256, 0, stream>>>(idx, tok, pos, x);

  if (full) {
    long long nsrc = (long long)Vm * Dm, ntot = (long long)VPAD * Dm;
    conv_k<<<(int)((ntot + 2047) / 2048), 256, 0, stream>>>(tok, tokbf, nsrc,
                                                            ntot);
  }

  for (int l = 0; l < Lm; ++l) {
    convw_k<<<(int)(WELEMS / 2048), 256, 0, stream>>>(
        qkvw + (size_t)l * R0, projw + (size_t)l * R1, fc1w + (size_t)l * R2,
        fc2w + (size_t)l * R3, wbuf);
    ln_k<<<Mm, 256, 0, stream>>>(x, ln1w + l * Dm, ln1b + l * Dm, h);
    launch_gemm(h, wbuf, qkvb + (size_t)l * 3 * Dm, nullptr, nullptr, big,
                3 * Dm, 3 * Dm, Dm, 0, Mm / 128, (3 * Dm) / 128, stream);
    vtr_k<<<dim3(Tm / 64, Bm * 16), 256, 0, stream>>>(big, vtG);
    attn_k<<<dim3(Tm / 64, Bm * 16), 256, 0, stream>>>(big, vtG, h);
    launch_gemm(h, wbuf + R0, projb + (size_t)l * Dm, x, x, nullptr, Dm, Dm,
                Dm, 0, Mm / 128, Dm / 128, stream);
    ln_k<<<Mm, 256, 0, stream>>>(x, ln2w + l * Dm, ln2b + l * Dm, h);
    launch_gemm(h, wbuf + R0 + R1, fc1b + (size_t)l * FFm, nullptr, nullptr,
                big, FFm, FFm, Dm, 1, Mm / 128, FFm / 128, stream);
    launch_gemm(big, wbuf + R0 + R1 + R2, fc2b + (size_t)l * Dm, x, x,
                nullptr, Dm, Dm, FFm, 0, Mm / 128, Dm / 128, stream);
  }

  ln_k<<<Mm, 256, 0, stream>>>(x, lnfw, lnfb, h);

  if (full) {
    launch_gemm(h, tokbf, nullptr, nullptr, out, nullptr, Vm, Vm, Dm, 0,
                Mm / 128, VPAD / 128, stream);
  } else {
    // chunked logits through wbuf
    for (int c0 = 0; c0 < VPAD; c0 += 6400) {
      int rows = VPAD - c0 < 6400 ? VPAD - c0 : 6400;
      long long nsrc = (long long)(Vm - c0 < rows ? (Vm - c0 > 0 ? Vm - c0 : 0)
                                                  : rows) *
                       Dm;
      long long ntot = (long long)rows * Dm;
      conv_k<<<(int)((ntot + 2047) / 2048), 256, 0, stream>>>(
          tok + (size_t)c0 * Dm, wbuf, nsrc, ntot);
      launch_gemm(h, wbuf, nullptr, nullptr, out + c0, nullptr, Vm, Vm - c0,
                  Dm, 0, Mm / 128, rows / 128, stream);
    }
  }
}

// Round 6
// 2548.564 us; speedup vs baseline: 1.0008x; 1.0008x over previous
//
#include <hip/hip_runtime.h>
#include <cstdint>

#define Dm 1024
#define Tm 1024
#define Bm 2
#define Lm 8
#define FFm 4096
#define Vm 50257
#define Mm (Bm * Tm)
#define VPAD 50304  // 393*128, zero-padded bf16 tok_emb rows

typedef __bf16 bf16x8 __attribute__((ext_vector_type(8)));
typedef float f32x4 __attribute__((ext_vector_type(4)));
typedef unsigned short u16;
typedef unsigned int u32;
typedef u16 u16x8 __attribute__((ext_vector_type(8)));
typedef u16 u16x4 __attribute__((ext_vector_type(4)));

__device__ __forceinline__ u16 f2bf(float f) {
  u32 u = __float_as_uint(f);
  u += 0x7FFFu + ((u >> 16) & 1u);
  return (u16)(u >> 16);
}
__device__ __forceinline__ float bf2f(u16 u) {
  return __uint_as_float((u32)u << 16);
}
__device__ __forceinline__ u32 packbf(float lo, float hi) {
  return (u32)f2bf(lo) | ((u32)f2bf(hi) << 16);
}

// async global->LDS, 16B per lane. LDS dest: wave-uniform base + lane*16.
__device__ __forceinline__ void gload16(const u16* g, u16* l) {
  __builtin_amdgcn_global_load_lds(
      (const __attribute__((address_space(1))) void*)g,
      (__attribute__((address_space(3))) void*)l, 16, 0, 0);
}

// ---------------- embedding ----------------
__global__ __launch_bounds__(256) void embed_k(
    const int* __restrict__ idx, const float* __restrict__ tok,
    const float* __restrict__ pos, float* __restrict__ x) {
  int m = blockIdx.x, t = threadIdx.x;
  int id = idx[m];
  int tt = m & (Tm - 1);
  float4 a = *(const float4*)(tok + (size_t)id * Dm + t * 4);
  float4 p = *(const float4*)(pos + (size_t)tt * Dm + t * 4);
  float4 o;
  o.x = a.x + p.x; o.y = a.y + p.y; o.z = a.z + p.z; o.w = a.w + p.w;
  *(float4*)(x + (size_t)m * Dm + t * 4) = o;
}

// ---------------- weight conversion fp32 -> bf16 ----------------
__global__ __launch_bounds__(256) void conv_k(const float* __restrict__ s,
                                              u16* __restrict__ d,
                                              long long nsrc, long long ntot) {
  long long i = ((long long)blockIdx.x * 256 + threadIdx.x) * 8;
  if (i >= ntot) return;
  u16x8 r = {0, 0, 0, 0, 0, 0, 0, 0};
  if (i < nsrc) {
    float4 a = *(const float4*)(s + i);
    float4 b = *(const float4*)(s + i + 4);
    r[0] = f2bf(a.x); r[1] = f2bf(a.y); r[2] = f2bf(a.z); r[3] = f2bf(a.w);
    r[4] = f2bf(b.x); r[5] = f2bf(b.y); r[6] = f2bf(b.z); r[7] = f2bf(b.w);
  }
  *(u16x8*)(d + i) = r;
}

#define R0 (3 * Dm * Dm)
#define R1 (Dm * Dm)
#define R2 (FFm * Dm)
#define R3 (Dm * FFm)
__global__ __launch_bounds__(256) void convw_k(
    const float* __restrict__ s0, const float* __restrict__ s1,
    const float* __restrict__ s2, const float* __restrict__ s3,
    u16* __restrict__ d) {
  size_t i = ((size_t)blockIdx.x * 256 + threadIdx.x) * 8;
  const float* s;
  size_t o;
  if (i < R0) { s = s0; o = i; }
  else if (i < (size_t)R0 + R1) { s = s1; o = i - R0; }
  else if (i < (size_t)R0 + R1 + R2) { s = s2; o = i - R0 - R1; }
  else { s = s3; o = i - R0 - R1 - R2; }
  float4 a = *(const float4*)(s + o);
  float4 b = *(const float4*)(s + o + 4);
  u16x8 r;
  r[0] = f2bf(a.x); r[1] = f2bf(a.y); r[2] = f2bf(a.z); r[3] = f2bf(a.w);
  r[4] = f2bf(b.x); r[5] = f2bf(b.y); r[6] = f2bf(b.z); r[7] = f2bf(b.w);
  *(u16x8*)(d + i) = r;
}

// ---------------- layernorm (fp32 in, bf16 out) ----------------
__global__ __launch_bounds__(256) void ln_k(const float* __restrict__ x,
                                            const float* __restrict__ w,
                                            const float* __restrict__ b,
                                            u16* __restrict__ out) {
  __shared__ float red[4];
  int row = blockIdx.x, t = threadIdx.x;
  float4 v = *(const float4*)(x + (size_t)row * Dm + t * 4);
  float s = v.x + v.y + v.z + v.w;
#pragma unroll
  for (int mm = 1; mm < 64; mm <<= 1) s += __shfl_xor(s, mm);
  if ((t & 63) == 0) red[t >> 6] = s;
  __syncthreads();
  float mu = (red[0] + red[1] + red[2] + red[3]) * (1.0f / Dm);
  __syncthreads();
  float dx = v.x - mu, dy = v.y - mu, dz = v.z - mu, dw = v.w - mu;
  float sq = dx * dx + dy * dy + dz * dz + dw * dw;
#pragma unroll
  for (int mm = 1; mm < 64; mm <<= 1) sq += __shfl_xor(sq, mm);
  if ((t & 63) == 0) red[t >> 6] = sq;
  __syncthreads();
  float var = (red[0] + red[1] + red[2] + red[3]) * (1.0f / Dm);
  float rs = rsqrtf(var + 1e-5f);
  float4 wv = *(const float4*)(w + t * 4);
  float4 bv = *(const float4*)(b + t * 4);
  u16x4 o;
  o[0] = f2bf(dx * rs * wv.x + bv.x);
  o[1] = f2bf(dy * rs * wv.y + bv.y);
  o[2] = f2bf(dz * rs * wv.z + bv.z);
  o[3] = f2bf(dw * rs * wv.w + bv.w);
  *(u16x4*)(out + (size_t)row * Dm + t * 4) = o;
}

// ---------------- GEMM: C[M,·] = A[M,K] @ W[·,K]^T ----------------
// 128x128 tile, 4 waves, BK=32, mfma 16x16x32 bf16.
// Double-buffered (T3 2-phase): STAGE(next) -> ds_read(cur)+MFMA -> barrier.
// global_load_lds width-16, source-chunk XOR swizzle (2-way = free).
__global__ __launch_bounds__(256) void gemm_k(
    const u16* __restrict__ A, const u16* __restrict__ W,
    const float* __restrict__ bias, const float* __restrict__ res,
    float* __restrict__ Cf, u16* __restrict__ Cb, int ldc, int nstore, int K,
    int gelu, int mblks, int nblks) {
  __shared__ __align__(16) u16 As[2][4096];
  __shared__ __align__(16) u16 Ws[2][4096];
  int id = blockIdx.x;
  int c = id & 7, m2 = id >> 3;
  int bx = m2 % mblks;
  int by = (m2 / mblks) * 8 + c;
  if (by >= nblks) return;
  int m0 = bx << 7, n0 = by << 7;
  int t = threadIdx.x;
  int wave = t >> 6, lane = t & 63;
  int wm = (wave & 1) << 6, wn = (wave >> 1) << 6;
  int lr = lane & 15, cq = lane >> 4;

  f32x4 acc[4][4] = {};

  int ch0 = wave * 64 + lane;
  int ch1 = 256 + ch0;
  int r0 = ch0 >> 2, c0 = (ch0 & 3) ^ ((r0 >> 1) & 3);
  int r1 = ch1 >> 2, c1 = (ch1 & 3) ^ ((r1 >> 1) & 3);
  const u16* gA0 = A + (size_t)(m0 + r0) * K + c0 * 8;
  const u16* gA1 = A + (size_t)(m0 + r1) * K + c1 * 8;
  const u16* gW0 = W + (size_t)(n0 + r0) * K + c0 * 8;
  const u16* gW1 = W + (size_t)(n0 + r1) * K + c1 * 8;

  int nst = K >> 5;
  // prologue: stage tile 0 into buf 0
  gload16(gA0, &As[0][wave * 512]);
  gload16(gA1, &As[0][2048 + wave * 512]);
  gload16(gW0, &Ws[0][wave * 512]);
  gload16(gW1, &Ws[0][2048 + wave * 512]);
  __syncthreads();

  for (int i = 0; i < nst; ++i) {
    int cur = i & 1;
    if (i + 1 < nst) {
      int ko = (i + 1) << 5;
      gload16(gA0 + ko, &As[cur ^ 1][wave * 512]);
      gload16(gA1 + ko, &As[cur ^ 1][2048 + wave * 512]);
      gload16(gW0 + ko, &Ws[cur ^ 1][wave * 512]);
      gload16(gW1 + ko, &Ws[cur ^ 1][2048 + wave * 512]);
    }
    bf16x8 af[4], bf[4];
#pragma unroll
    for (int mi = 0; mi < 4; ++mi) {
      int rr = wm + mi * 16 + lr;
      af[mi] =
          *(const bf16x8*)&As[cur][rr * 32 + ((cq ^ ((rr >> 1) & 3)) << 3)];
    }
#pragma unroll
    for (int ni = 0; ni < 4; ++ni) {
      int rr = wn + ni * 16 + lr;
      bf[ni] =
          *(const bf16x8*)&Ws[cur][rr * 32 + ((cq ^ ((rr >> 1) & 3)) << 3)];
    }
#pragma unroll
    for (int mi = 0; mi < 4; ++mi)
#pragma unroll
      for (int ni = 0; ni < 4; ++ni)
        acc[mi][ni] = __builtin_amdgcn_mfma_f32_16x16x32_bf16(
            af[mi], bf[ni], acc[mi][ni], 0, 0, 0);
    __syncthreads();
  }

  // epilogue: C/D layout col=lane&15, row=(lane>>4)*4+reg [m89]
  int orow = cq << 2, ocol = lr;
#pragma unroll
  for (int mi = 0; mi < 4; ++mi) {
#pragma unroll
    for (int ni = 0; ni < 4; ++ni) {
      int gm = m0 + wm + mi * 16 + orow;
      int gn = n0 + wn + ni * 16 + ocol;
      if (gn < nstore) {
        float bv = bias ? bias[gn] : 0.f;
#pragma unroll
        for (int j = 0; j < 4; ++j) {
          float o = acc[mi][ni][j] + bv;
          if (gelu) o = 0.5f * o * (1.0f + erff(o * 0.70710678118654752f));
          if (res) o += res[(size_t)(gm + j) * ldc + gn];
          if (Cb) Cb[(size_t)(gm + j) * ldc + gn] = f2bf(o);
          else Cf[(size_t)(gm + j) * ldc + gn] = o;
        }
      }
    }
  }
}

// ---------------- V transpose: qkv V-part -> vt[bh][d][t] ----------------
__global__ __launch_bounds__(256) void vtr_k(const u16* __restrict__ qkv,
                                             u16* __restrict__ vt) {
  __shared__ u16 T[64 * 68];
  int bh = blockIdx.y;
  int b = bh >> 4, h = bh & 15;
  int t0 = blockIdx.x << 6;
  int tid = threadIdx.x;
  int r = tid >> 2, q4 = tid & 3;
  const u16* src = qkv + (size_t)(b * Tm + t0 + r) * 3072 + 2048 + h * 64 +
                   q4 * 16;
  *(u16x8*)&T[r * 68 + q4 * 16] = *(const u16x8*)src;
  *(u16x8*)&T[r * 68 + q4 * 16 + 8] = *(const u16x8*)(src + 8);
  __syncthreads();
  int dr = tid >> 2, kq = tid & 3;
  u16x8 o0, o1;
#pragma unroll
  for (int u = 0; u < 8; ++u) o0[u] = T[(kq * 16 + u) * 68 + dr];
#pragma unroll
  for (int u = 0; u < 8; ++u) o1[u] = T[(kq * 16 + 8 + u) * 68 + dr];
  u16* dst = vt + ((size_t)bh * 64 + dr) * 1024 + t0 + kq * 16;
  *(u16x8*)dst = o0;
  *(u16x8*)(dst + 8) = o1;
}

// ---------------- MFMA flash attention v2 ----------------
// Swapped QK^T: s = mfma(K,Q) -> S^T, q = lane&15 -> softmax is 16 in-lane
// values + 2 shfl_xor. P stays in-register; 16-shuffle redistribution into
// the PV A-operand layout. V pre-transposed globally (vt), staged linearly.
// K/V double-buffered; 1 barrier per tile.
__global__ __launch_bounds__(256) void attn_k(const u16* __restrict__ qkv,
                                              const u16* __restrict__ vt,
                                              u16* __restrict__ y) {
  __shared__ __align__(16) u16 Ks[2][4096];
  __shared__ __align__(16) u16 Vs[2][4096];
  int qt = gridDim.x - 1 - blockIdx.x;  // big blocks first
  int q0 = qt << 6;
  int bh = blockIdx.y;
  int b = bh >> 4, h = bh & 15;
  int t = threadIdx.x, wave = t >> 6, lane = t & 63;
  int lr = lane & 15, cq = lane >> 4;

  // Q fragments (B-operand), pre-scaled by 1/8 (exact in bf16)
  bf16x8 qf[2];
  {
    size_t base = (size_t)(b * Tm + q0 + wave * 16 + lr) * 3072 + h * 64;
#pragma unroll
    for (int ks = 0; ks < 2; ++ks) {
      u16x8 qa = *(const u16x8*)(qkv + base + ks * 32 + cq * 8);
#pragma unroll
      for (int u = 0; u < 8; ++u) qa[u] = f2bf(bf2f(qa[u]) * 0.125f);
      qf[ks] = *(bf16x8*)&qa;
    }
  }

  f32x4 accO[4] = {};
  float m_run = -1e30f, l_run = 0.f;  // per lane, stats for q = lr

  // staging addresses
  int ch0 = wave * 64 + lane, ch1 = 256 + ch0;
  int kr0 = ch0 >> 3, kc0 = ((ch0 & 7) ^ (kr0 & 7)) << 3;
  int kr1 = ch1 >> 3, kc1 = ((ch1 & 7) ^ (kr1 & 7)) << 3;
  const u16* kbase = qkv + (size_t)b * Tm * 3072 + 1024 + h * 64;
  const u16* vbase = vt + (size_t)bh * 64 * 1024;

  {
    // prologue: stage tile 0 into buf 0
    gload16(kbase + (size_t)kr0 * 3072 + kc0, &Ks[0][wave * 512]);
    gload16(kbase + (size_t)kr1 * 3072 + kc1, &Ks[0][2048 + wave * 512]);
    gload16(vbase + (size_t)kr0 * 1024 + kc0, &Vs[0][wave * 512]);
    gload16(vbase + (size_t)kr1 * 1024 + kc1, &Vs[0][2048 + wave * 512]);
  }
  __syncthreads();

  for (int tk = 0; tk <= qt; ++tk) {
    int cur = tk & 1;
    if (tk < qt) {
      int kb0 = (tk + 1) << 6;
      gload16(kbase + (size_t)(kb0 + kr0) * 3072 + kc0,
              &Ks[cur ^ 1][wave * 512]);
      gload16(kbase + (size_t)(kb0 + kr1) * 3072 + kc1,
              &Ks[cur ^ 1][2048 + wave * 512]);
      gload16(vbase + (size_t)kr0 * 1024 + kb0 + kc0,
              &Vs[cur ^ 1][wave * 512]);
      gload16(vbase + (size_t)kr1 * 1024 + kb0 + kc1,
              &Vs[cur ^ 1][2048 + wave * 512]);
    }

    // S^T = K Q^T : s[ni][r] = S[kk = ni*16 + cq*4 + r][q = lr]
    f32x4 s[4] = {};
    __builtin_amdgcn_s_setprio(1);
#pragma unroll
    for (int ks = 0; ks < 2; ++ks)
#pragma unroll
      for (int ni = 0; ni < 4; ++ni) {
        int rk = ni * 16 + lr;
        int ck = ks * 4 + cq;
        bf16x8 kf = *(const bf16x8*)&Ks[cur][rk * 64 + ((ck ^ (rk & 7)) << 3)];
        s[ni] = __builtin_amdgcn_mfma_f32_16x16x32_bf16(kf, qf[ks], s[ni],
                                                        0, 0, 0);
      }
    __builtin_amdgcn_s_setprio(0);

    if (tk == qt) {  // causal mask, last tile only
      int kb0 = tk << 6;
      int qa = q0 + wave * 16 + lr;
#pragma unroll
      for (int ni = 0; ni < 4; ++ni)
#pragma unroll
        for (int r = 0; r < 4; ++r)
          if (kb0 + ni * 16 + cq * 4 + r > qa) s[ni][r] = -1e30f;
    }

    // online softmax: 16 in-lane values (all for q = lr)
    float mx = fmaxf(fmaxf(s[0][0], s[0][1]), fmaxf(s[0][2], s[0][3]));
#pragma unroll
    for (int ni = 1; ni < 4; ++ni)
      mx = fmaxf(mx, fmaxf(fmaxf(s[ni][0], s[ni][1]),
                           fmaxf(s[ni][2], s[ni][3])));
    mx = fmaxf(mx, __shfl_xor(mx, 16));
    mx = fmaxf(mx, __shfl_xor(mx, 32));
    float mn = fmaxf(m_run, mx);
    float alpha = __expf(m_run - mn);
    m_run = mn;
    float ls = 0.f;
    u32 packed[4][2];
#pragma unroll
    for (int ni = 0; ni < 4; ++ni) {
      float p0 = __expf(s[ni][0] - mn), p1 = __expf(s[ni][1] - mn);
      float p2 = __expf(s[ni][2] - mn), p3 = __expf(s[ni][3] - mn);
      ls += (p0 + p1) + (p2 + p3);
      packed[ni][0] = packbf(p0, p1);
      packed[ni][1] = packbf(p2, p3);
    }
    ls += __shfl_xor(ls, 16);
    ls += __shfl_xor(ls, 32);
    l_run = l_run * alpha + ls;

    // rescale O by alpha of q = cq*4+j (stats live at lane lr = q)
#pragma unroll
    for (int j = 0; j < 4; ++j) {
      float a = __shfl(alpha, (cq << 2) + j);
#pragma unroll
      for (int di = 0; di < 4; ++di) accO[di][j] *= a;
    }

    // P redistribution: target lane (lr,cq) needs P[q=lr][k=ks2*32+cq*8+e]
    // source: packed[2*ks2 + (cq>>1)][w&1] at lane lr + 16*((cq&1)*2+(w>>1))
    bf16x8 pf[2];
#pragma unroll
    for (int ks2 = 0; ks2 < 2; ++ks2) {
      union { u32 w[4]; bf16x8 v; } pu;
#pragma unroll
      for (int w = 0; w < 4; ++w) {
        int src = lr + 16 * (((cq & 1) << 1) + (w >> 1));
        int a = __shfl((int)packed[2 * ks2][w & 1], src);
        int bb = __shfl((int)packed[2 * ks2 + 1][w & 1], src);
        pu.w[w] = (cq >> 1) ? (u32)bb : (u32)a;
      }
      pf[ks2] = pu.v;
    }

    // O += P V : accO[di] = O[q = cq*4+j][d = di*16+lr]
    __builtin_amdgcn_s_setprio(1);
#pragma unroll
    for (int ks2 = 0; ks2 < 2; ++ks2)
#pragma unroll
      for (int di = 0; di < 4; ++di) {
        int rv = di * 16 + lr;
        int ck = ks2 * 4 + cq;
        bf16x8 vf = *(const bf16x8*)&Vs[cur][rv * 64 + ((ck ^ (rv & 7)) << 3)];
        accO[di] = __builtin_amdgcn_mfma_f32_16x16x32_bf16(pf[ks2], vf,
                                                           accO[di], 0, 0, 0);
      }
    __builtin_amdgcn_s_setprio(0);
    __syncthreads();
  }

  float iv = 1.0f / l_run;
  int qrow = q0 + wave * 16 + (cq << 2);
#pragma unroll
  for (int j = 0; j < 4; ++j) {
    float ivj = __shfl(iv, (cq << 2) + j);
    size_t row = (size_t)(b * Tm + qrow + j) * Dm + h * 64;
#pragma unroll
    for (int di = 0; di < 4; ++di)
      y[row + di * 16 + lr] = f2bf(accO[di][j] * ivj);
  }
}

// ---------------- host ----------------
#define WELEMS ((size_t)(R0 + R1 + R2 + R3))  // 12Mi elems per layer

static inline void launch_gemm(const u16* A, const u16* W, const float* bias,
                               const float* res, float* Cf, u16* Cb, int ldc,
                               int nstore, int K, int gelu, int mblks,
                               int nblks, hipStream_t stream) {
  int gx = 8 * mblks * ((nblks + 7) / 8);
  gemm_k<<<gx, 256, 0, stream>>>(A, W, bias, res, Cf, Cb, ldc, nstore, K,
                                 gelu, mblks, nblks);
}

extern "C" void kernel_launch(void* const* d_in, const int* in_sizes, int n_in,
                              void* d_out, int out_size, void* d_ws,
                              size_t ws_size, hipStream_t stream) {
  const int* idx = (const int*)d_in[0];
  const float* tok = (const float*)d_in[1];
  const float* pos = (const float*)d_in[2];
  const float* ln1w = (const float*)d_in[3];
  const float* ln1b = (const float*)d_in[4];
  const float* qkvw = (const float*)d_in[5];
  const float* qkvb = (const float*)d_in[6];
  const float* projw = (const float*)d_in[7];
  const float* projb = (const float*)d_in[8];
  const float* ln2w = (const float*)d_in[9];
  const float* ln2b = (const float*)d_in[10];
  const float* fc1w = (const float*)d_in[11];
  const float* fc1b = (const float*)d_in[12];
  const float* fc2w = (const float*)d_in[13];
  const float* fc2b = (const float*)d_in[14];
  const float* lnfw = (const float*)d_in[15];
  const float* lnfb = (const float*)d_in[16];
  float* out = (float*)d_out;

  // ws layout
  char* w = (char*)d_ws;
  float* x = (float*)w;  w += (size_t)Mm * Dm * 4;   // 8 MB fp32 residual
  u16* h = (u16*)w;      w += (size_t)Mm * Dm * 2;   // 4 MB LN-out / attn-out
  u16* big = (u16*)w;    w += (size_t)Mm * FFm * 2;  // 16 MB qkv/ff union
  u16* vtG = (u16*)w;    w += (size_t)Bm * 16 * 64 * Tm * 2;  // 4 MB V^T
  u16* wbuf = (u16*)w;   w += WELEMS * 2;            // 24 MB layer weights
  u16* tokbf = (u16*)w;
  size_t need_full = (size_t)(w - (char*)d_ws) + (size_t)VPAD * Dm * 2;
  bool full = ws_size >= need_full;

  embed_k<<<Mm, 256, 0, stream>>>(idx, tok, pos, x);

  if (full) {
    long long nsrc = (long long)Vm * Dm, ntot = (long long)VPAD * Dm;
    conv_k<<<(int)((ntot + 2047) / 2048), 256, 0, stream>>>(tok, tokbf, nsrc,
                                                            ntot);
  }

  for (int l = 0; l < Lm; ++l) {
    convw_k<<<(int)(WELEMS / 2048), 256, 0, stream>>>(
        qkvw + (size_t)l * R0, projw + (size_t)l * R1, fc1w + (size_t)l * R2,
        fc2w + (size_t)l * R3, wbuf);
    ln_k<<<Mm, 256, 0, stream>>>(x, ln1w + l * Dm, ln1b + l * Dm, h);
    launch_gemm(h, wbuf, qkvb + (size_t)l * 3 * Dm, nullptr, nullptr, big,
                3 * Dm, 3 * Dm, Dm, 0, Mm / 128, (3 * Dm) / 128, stream);
    vtr_k<<<dim3(Tm / 64, Bm * 16), 256, 0, stream>>>(big, vtG);
    attn_k<<<dim3(Tm / 64, Bm * 16), 256, 0, stream>>>(big, vtG, h);
    launch_gemm(h, wbuf + R0, projb + (size_t)l * Dm, x, x, nullptr, Dm, Dm,
                Dm, 0, Mm / 128, Dm / 128, stream);
    ln_k<<<Mm, 256, 0, stream>>>(x, ln2w + l * Dm, ln2b + l * Dm, h);
    launch_gemm(h, wbuf + R0 + R1, fc1b + (size_t)l * FFm, nullptr, nullptr,
                big, FFm, FFm, Dm, 1, Mm / 128, FFm / 128, stream);
    launch_gemm(big, wbuf + R0 + R1 + R2, fc2b + (size_t)l * Dm, x, x,
                nullptr, Dm, Dm, FFm, 0, Mm / 128, Dm / 128, stream);
  }

  ln_k<<<Mm, 256, 0, stream>>>(x, lnfw, lnfb, h);

  if (full) {
    launch_gemm(h, tokbf, nullptr, nullptr, out, nullptr, Vm, Vm, Dm, 0,
                Mm / 128, VPAD / 128, stream);
  } else {
    // chunked logits through wbuf
    for (int c0 = 0; c0 < VPAD; c0 += 6400) {
      int rows = VPAD - c0 < 6400 ? VPAD - c0 : 6400;
      long long nsrc = (long long)(Vm - c0 < rows ? (Vm - c0 > 0 ? Vm - c0 : 0)
                                                  : rows) *
                       Dm;
      long long ntot = (long long)rows * Dm;
      conv_k<<<(int)((ntot + 2047) / 2048), 256, 0, stream>>>(
          tok + (size_t)c0 * Dm, wbuf, nsrc, ntot);
      launch_gemm(h, wbuf, nullptr, nullptr, out + c0, nullptr, Vm, Vm - c0,
                  Dm, 0, Mm / 128, rows / 128, stream);
    }
  }
}

// Round 7
// 2167.809 us; speedup vs baseline: 1.1765x; 1.1756x over previous
//
#include <hip/hip_runtime.h>
#include <cstdint>

#define Dm 1024
#define Tm 1024
#define Bm 2
#define Lm 8
#define FFm 4096
#define Vm 50257
#define Mm (Bm * Tm)
#define VPAD2 50432  // 197*256, zero-padded bf16 tok_emb rows

typedef __bf16 bf16x8 __attribute__((ext_vector_type(8)));
typedef float f32x4 __attribute__((ext_vector_type(4)));
typedef unsigned short u16;
typedef unsigned int u32;
typedef u16 u16x8 __attribute__((ext_vector_type(8)));
typedef u16 u16x4 __attribute__((ext_vector_type(4)));

__device__ __forceinline__ u16 f2bf(float f) {
  u32 u = __float_as_uint(f);
  u += 0x7FFFu + ((u >> 16) & 1u);
  return (u16)(u >> 16);
}
__device__ __forceinline__ float bf2f(u16 u) {
  return __uint_as_float((u32)u << 16);
}
__device__ __forceinline__ u32 packbf(float lo, float hi) {
  return (u32)f2bf(lo) | ((u32)f2bf(hi) << 16);
}

// async global->LDS, 16B per lane. LDS dest: wave-uniform base + lane*16.
__device__ __forceinline__ void gload16(const u16* g, u16* l) {
  __builtin_amdgcn_global_load_lds(
      (const __attribute__((address_space(1))) void*)g,
      (__attribute__((address_space(3))) void*)l, 16, 0, 0);
}

// ---------------- embedding ----------------
__global__ __launch_bounds__(256) void embed_k(
    const int* __restrict__ idx, const float* __restrict__ tok,
    const float* __restrict__ pos, float* __restrict__ x) {
  int m = blockIdx.x, t = threadIdx.x;
  int id = idx[m];
  int tt = m & (Tm - 1);
  float4 a = *(const float4*)(tok + (size_t)id * Dm + t * 4);
  float4 p = *(const float4*)(pos + (size_t)tt * Dm + t * 4);
  float4 o;
  o.x = a.x + p.x; o.y = a.y + p.y; o.z = a.z + p.z; o.w = a.w + p.w;
  *(float4*)(x + (size_t)m * Dm + t * 4) = o;
}

// ---------------- weight conversion fp32 -> bf16 ----------------
__global__ __launch_bounds__(256) void conv_k(const float* __restrict__ s,
                                              u16* __restrict__ d,
                                              long long nsrc, long long ntot) {
  long long i = ((long long)blockIdx.x * 256 + threadIdx.x) * 8;
  if (i >= ntot) return;
  u16x8 r = {0, 0, 0, 0, 0, 0, 0, 0};
  if (i < nsrc) {
    float4 a = *(const float4*)(s + i);
    float4 b = *(const float4*)(s + i + 4);
    r[0] = f2bf(a.x); r[1] = f2bf(a.y); r[2] = f2bf(a.z); r[3] = f2bf(a.w);
    r[4] = f2bf(b.x); r[5] = f2bf(b.y); r[6] = f2bf(b.z); r[7] = f2bf(b.w);
  }
  *(u16x8*)(d + i) = r;
}

#define R0 (3 * Dm * Dm)
#define R1 (Dm * Dm)
#define R2 (FFm * Dm)
#define R3 (Dm * FFm)
__global__ __launch_bounds__(256) void convw_k(
    const float* __restrict__ s0, const float* __restrict__ s1,
    const float* __restrict__ s2, const float* __restrict__ s3,
    u16* __restrict__ d) {
  size_t i = ((size_t)blockIdx.x * 256 + threadIdx.x) * 8;
  const float* s;
  size_t o;
  if (i < R0) { s = s0; o = i; }
  else if (i < (size_t)R0 + R1) { s = s1; o = i - R0; }
  else if (i < (size_t)R0 + R1 + R2) { s = s2; o = i - R0 - R1; }
  else { s = s3; o = i - R0 - R1 - R2; }
  float4 a = *(const float4*)(s + o);
  float4 b = *(const float4*)(s + o + 4);
  u16x8 r;
  r[0] = f2bf(a.x); r[1] = f2bf(a.y); r[2] = f2bf(a.z); r[3] = f2bf(a.w);
  r[4] = f2bf(b.x); r[5] = f2bf(b.y); r[6] = f2bf(b.z); r[7] = f2bf(b.w);
  *(u16x8*)(d + i) = r;
}

// ---------------- layernorm (fp32 in, bf16 out) ----------------
__global__ __launch_bounds__(256) void ln_k(const float* __restrict__ x,
                                            const float* __restrict__ w,
                                            const float* __restrict__ b,
                                            u16* __restrict__ out) {
  __shared__ float red[4];
  int row = blockIdx.x, t = threadIdx.x;
  float4 v = *(const float4*)(x + (size_t)row * Dm + t * 4);
  float s = v.x + v.y + v.z + v.w;
#pragma unroll
  for (int mm = 1; mm < 64; mm <<= 1) s += __shfl_xor(s, mm);
  if ((t & 63) == 0) red[t >> 6] = s;
  __syncthreads();
  float mu = (red[0] + red[1] + red[2] + red[3]) * (1.0f / Dm);
  __syncthreads();
  float dx = v.x - mu, dy = v.y - mu, dz = v.z - mu, dw = v.w - mu;
  float sq = dx * dx + dy * dy + dz * dz + dw * dw;
#pragma unroll
  for (int mm = 1; mm < 64; mm <<= 1) sq += __shfl_xor(sq, mm);
  if ((t & 63) == 0) red[t >> 6] = sq;
  __syncthreads();
  float var = (red[0] + red[1] + red[2] + red[3]) * (1.0f / Dm);
  float rs = rsqrtf(var + 1e-5f);
  float4 wv = *(const float4*)(w + t * 4);
  float4 bv = *(const float4*)(b + t * 4);
  u16x4 o;
  o[0] = f2bf(dx * rs * wv.x + bv.x);
  o[1] = f2bf(dy * rs * wv.y + bv.y);
  o[2] = f2bf(dz * rs * wv.z + bv.z);
  o[3] = f2bf(dw * rs * wv.w + bv.w);
  *(u16x4*)(out + (size_t)row * Dm + t * 4) = o;
}

// ============ gemm8_k: 256x256 tile, 8 waves, 8-phase counted-vmcnt ========
// K in 32-chunks cycling 4 LDS slots (128 KB). Per chunk: 2 phases x 16 MFMA.
// Prefetch issued 3 chunks ahead (A-half in phase A, W-half in phase B).
// Raw s_barrier + graded s_waitcnt vmcnt(8/4/0) -- never drains in steady
// state. Slot write-window proof: slot(c+3)'s prior occupant (c-1) was last
// read in chunk c-1 phase B (lgkmcnt(0) before its closing barrier), and
// chunk c's issues come after that barrier.
__global__ __launch_bounds__(512, 2) void gemm8_k(
    const u16* __restrict__ A, const u16* __restrict__ W,
    const float* __restrict__ bias, float* __restrict__ Cf,
    u16* __restrict__ Cb, int ldc, int nstore, int K, int gelu, int mblks,
    int nblks) {
  __shared__ __align__(16) u16 As[4][8192];
  __shared__ __align__(16) u16 Ws[4][8192];
  int nwg = mblks * nblks;
  int orig = blockIdx.x;
  int q8 = nwg >> 3, r8 = nwg & 7, xcd = orig & 7, loc = orig >> 3;
  int wg = (xcd < r8 ? xcd * (q8 + 1) : r8 * (q8 + 1) + (xcd - r8) * q8) + loc;
  int bx = wg % mblks, by = wg / mblks;
  int m0 = bx << 8, n0 = by << 8;
  int t = threadIdx.x, wave = t >> 6, lane = t & 63;
  int wr = wave >> 2, wc = wave & 3;
  int lr = lane & 15, cq = lane >> 4;
  // staging: thread -> (row0 = t>>2 in [0,128), kc = t&3), rounds r=0/1 add
  // 128 rows. Source chunk-col XOR-swizzled (involution), LDS linear.
  int row0 = t >> 2;
  int kcG = (t & 3) ^ ((t >> 3) & 3);
  const u16* gA = A + (size_t)(m0 + row0) * K + kcG * 8;
  const u16* gW = W + (size_t)(n0 + row0) * K + kcG * 8;
  size_t rstep = (size_t)128 * K;

  f32x4 acc[8][4] = {};
  int nch = K >> 5;

  // prologue: chunks 0..2 (12 loads/thread)
  for (int s = 0; s < 3; ++s) {
    gload16(gA + s * 32, &As[s][wave * 512]);
    gload16(gA + rstep + s * 32, &As[s][4096 + wave * 512]);
    gload16(gW + s * 32, &Ws[s][wave * 512]);
    gload16(gW + rstep + s * 32, &Ws[s][4096 + wave * 512]);
  }
  asm volatile("s_waitcnt vmcnt(8)" ::: "memory");  // chunk 0 resident
  __builtin_amdgcn_s_barrier();

  for (int c = 0; c < nch; ++c) {
    const u16* sA = As[c & 3];
    const u16* sW = Ws[c & 3];
    bf16x8 afr[4], bfr[4];
    // ---------- phase A: m-frags 0-3 ----------
#pragma unroll
    for (int mi = 0; mi < 4; ++mi) {
      int rowm = wr * 128 + mi * 16 + lr;
      afr[mi] =
          *(const bf16x8*)&sA[rowm * 32 + ((cq ^ ((rowm >> 1) & 3)) << 3)];
    }
#pragma unroll
    for (int ni = 0; ni < 4; ++ni) {
      int rown = wc * 64 + ni * 16 + lr;
      bfr[ni] =
          *(const bf16x8*)&sW[rown * 32 + ((cq ^ ((rown >> 1) & 3)) << 3)];
    }
    if (c + 3 < nch) {
      int s3 = (c + 3) & 3;
      gload16(gA + (size_t)(c + 3) * 32, &As[s3][wave * 512]);
      gload16(gA + rstep + (size_t)(c + 3) * 32, &As[s3][4096 + wave * 512]);
    }
    __builtin_amdgcn_s_barrier();
    asm volatile("s_waitcnt lgkmcnt(0)" ::: "memory");
    __builtin_amdgcn_sched_barrier(0);
    __builtin_amdgcn_s_setprio(1);
#pragma unroll
    for (int mi = 0; mi < 4; ++mi)
#pragma unroll
      for (int ni = 0; ni < 4; ++ni)
        acc[mi][ni] = __builtin_amdgcn_mfma_f32_16x16x32_bf16(
            afr[mi], bfr[ni], acc[mi][ni], 0, 0, 0);
    __builtin_amdgcn_s_setprio(0);
    __builtin_amdgcn_s_barrier();
    // ---------- phase B: m-frags 4-7 (bfr reused) ----------
#pragma unroll
    for (int mi = 0; mi < 4; ++mi) {
      int rowm = wr * 128 + (mi + 4) * 16 + lr;
      afr[mi] =
          *(const bf16x8*)&sA[rowm * 32 + ((cq ^ ((rowm >> 1) & 3)) << 3)];
    }
    if (c + 3 < nch) {
      int s3 = (c + 3) & 3;
      gload16(gW + (size_t)(c + 3) * 32, &Ws[s3][wave * 512]);
      gload16(gW + rstep + (size_t)(c + 3) * 32, &Ws[s3][4096 + wave * 512]);
    }
    __builtin_amdgcn_s_barrier();
    asm volatile("s_waitcnt lgkmcnt(0)" ::: "memory");
    __builtin_amdgcn_sched_barrier(0);
    __builtin_amdgcn_s_setprio(1);
#pragma unroll
    for (int mi = 0; mi < 4; ++mi)
#pragma unroll
      for (int ni = 0; ni < 4; ++ni)
        acc[mi + 4][ni] = __builtin_amdgcn_mfma_f32_16x16x32_bf16(
            afr[mi], bfr[ni], acc[mi + 4][ni], 0, 0, 0);
    __builtin_amdgcn_s_setprio(0);
    // graded wait: ensure chunk c+1 resident behind the newest 8/4/0 loads
    if (c + 1 < nch) {
      if (c + 3 < nch)
        asm volatile("s_waitcnt vmcnt(8)" ::: "memory");
      else if (c + 2 < nch)
        asm volatile("s_waitcnt vmcnt(4)" ::: "memory");
      else
        asm volatile("s_waitcnt vmcnt(0)" ::: "memory");
    }
    __builtin_amdgcn_s_barrier();
  }

  // epilogue: C/D layout col=lane&15, row=(lane>>4)*4+reg [m89]
  int gm0 = m0 + wr * 128 + (cq << 2);
  int gn0 = n0 + wc * 64 + lr;
#pragma unroll
  for (int mi = 0; mi < 8; ++mi) {
#pragma unroll
    for (int ni = 0; ni < 4; ++ni) {
      int gm = gm0 + mi * 16;
      int gn = gn0 + ni * 16;
      if (gn < nstore) {
        float bv = bias ? bias[gn] : 0.f;
#pragma unroll
        for (int j = 0; j < 4; ++j) {
          float o = acc[mi][ni][j] + bv;
          if (gelu) o = 0.5f * o * (1.0f + erff(o * 0.70710678118654752f));
          if (Cb) Cb[(size_t)(gm + j) * ldc + gn] = f2bf(o);
          else Cf[(size_t)(gm + j) * ldc + gn] = o;
        }
      }
    }
  }
}

// ---------------- GEMM 128x128 (as r2-r6, for qkv + fallback) ----------------
__global__ __launch_bounds__(256) void gemm_k(
    const u16* __restrict__ A, const u16* __restrict__ W,
    const float* __restrict__ bias, const float* __restrict__ res,
    float* __restrict__ Cf, u16* __restrict__ Cb, int ldc, int nstore, int K,
    int gelu, int mblks, int nblks) {
  __shared__ __align__(16) u16 As[2][4096];
  __shared__ __align__(16) u16 Ws[2][4096];
  int id = blockIdx.x;
  int c = id & 7, m2 = id >> 3;
  int bx = m2 % mblks;
  int by = (m2 / mblks) * 8 + c;
  if (by >= nblks) return;
  int m0 = bx << 7, n0 = by << 7;
  int t = threadIdx.x;
  int wave = t >> 6, lane = t & 63;
  int wm = (wave & 1) << 6, wn = (wave >> 1) << 6;
  int lr = lane & 15, cq = lane >> 4;

  f32x4 acc[4][4] = {};

  int ch0 = wave * 64 + lane;
  int ch1 = 256 + ch0;
  int r0 = ch0 >> 2, c0 = (ch0 & 3) ^ ((r0 >> 1) & 3);
  int r1 = ch1 >> 2, c1 = (ch1 & 3) ^ ((r1 >> 1) & 3);
  const u16* gA0 = A + (size_t)(m0 + r0) * K + c0 * 8;
  const u16* gA1 = A + (size_t)(m0 + r1) * K + c1 * 8;
  const u16* gW0 = W + (size_t)(n0 + r0) * K + c0 * 8;
  const u16* gW1 = W + (size_t)(n0 + r1) * K + c1 * 8;

  int nst = K >> 5;
  gload16(gA0, &As[0][wave * 512]);
  gload16(gA1, &As[0][2048 + wave * 512]);
  gload16(gW0, &Ws[0][wave * 512]);
  gload16(gW1, &Ws[0][2048 + wave * 512]);
  __syncthreads();

  for (int i = 0; i < nst; ++i) {
    int cur = i & 1;
    if (i + 1 < nst) {
      int ko = (i + 1) << 5;
      gload16(gA0 + ko, &As[cur ^ 1][wave * 512]);
      gload16(gA1 + ko, &As[cur ^ 1][2048 + wave * 512]);
      gload16(gW0 + ko, &Ws[cur ^ 1][wave * 512]);
      gload16(gW1 + ko, &Ws[cur ^ 1][2048 + wave * 512]);
    }
    bf16x8 af[4], bf[4];
#pragma unroll
    for (int mi = 0; mi < 4; ++mi) {
      int rr = wm + mi * 16 + lr;
      af[mi] =
          *(const bf16x8*)&As[cur][rr * 32 + ((cq ^ ((rr >> 1) & 3)) << 3)];
    }
#pragma unroll
    for (int ni = 0; ni < 4; ++ni) {
      int rr = wn + ni * 16 + lr;
      bf[ni] =
          *(const bf16x8*)&Ws[cur][rr * 32 + ((cq ^ ((rr >> 1) & 3)) << 3)];
    }
#pragma unroll
    for (int mi = 0; mi < 4; ++mi)
#pragma unroll
      for (int ni = 0; ni < 4; ++ni)
        acc[mi][ni] = __builtin_amdgcn_mfma_f32_16x16x32_bf16(
            af[mi], bf[ni], acc[mi][ni], 0, 0, 0);
    __syncthreads();
  }

  int orow = cq << 2, ocol = lr;
#pragma unroll
  for (int mi = 0; mi < 4; ++mi) {
#pragma unroll
    for (int ni = 0; ni < 4; ++ni) {
      int gm = m0 + wm + mi * 16 + orow;
      int gn = n0 + wn + ni * 16 + ocol;
      if (gn < nstore) {
        float bv = bias ? bias[gn] : 0.f;
#pragma unroll
        for (int j = 0; j < 4; ++j) {
          float o = acc[mi][ni][j] + bv;
          if (gelu) o = 0.5f * o * (1.0f + erff(o * 0.70710678118654752f));
          if (res) o += res[(size_t)(gm + j) * ldc + gn];
          if (Cb) Cb[(size_t)(gm + j) * ldc + gn] = f2bf(o);
          else Cf[(size_t)(gm + j) * ldc + gn] = o;
        }
      }
    }
  }
}

// ---------------- split-K GEMM 128x128, atomicAdd epilogue ----------------
// C[gm,gn] += partial (+bias on kslice 0). C must hold the residual base.
__global__ __launch_bounds__(256) void gemmsk_k(
    const u16* __restrict__ A, const u16* __restrict__ W,
    const float* __restrict__ bias, float* __restrict__ C, int ldc, int K,
    int klen, int mblks, int nblks) {
  __shared__ __align__(16) u16 As[2][4096];
  __shared__ __align__(16) u16 Ws[2][4096];
  int id = blockIdx.x;
  int bx = id % mblks;
  int tmp = id / mblks;
  int by = tmp % nblks;
  int ks = tmp / nblks;
  int m0 = bx << 7, n0 = by << 7;
  int koff = ks * klen;
  int t = threadIdx.x;
  int wave = t >> 6, lane = t & 63;
  int wm = (wave & 1) << 6, wn = (wave >> 1) << 6;
  int lr = lane & 15, cq = lane >> 4;

  f32x4 acc[4][4] = {};

  int ch0 = wave * 64 + lane;
  int ch1 = 256 + ch0;
  int r0 = ch0 >> 2, c0 = (ch0 & 3) ^ ((r0 >> 1) & 3);
  int r1 = ch1 >> 2, c1 = (ch1 & 3) ^ ((r1 >> 1) & 3);
  const u16* gA0 = A + (size_t)(m0 + r0) * K + koff + c0 * 8;
  const u16* gA1 = A + (size_t)(m0 + r1) * K + koff + c1 * 8;
  const u16* gW0 = W + (size_t)(n0 + r0) * K + koff + c0 * 8;
  const u16* gW1 = W + (size_t)(n0 + r1) * K + koff + c1 * 8;

  int nst = klen >> 5;
  gload16(gA0, &As[0][wave * 512]);
  gload16(gA1, &As[0][2048 + wave * 512]);
  gload16(gW0, &Ws[0][wave * 512]);
  gload16(gW1, &Ws[0][2048 + wave * 512]);
  __syncthreads();

  for (int i = 0; i < nst; ++i) {
    int cur = i & 1;
    if (i + 1 < nst) {
      int ko = (i + 1) << 5;
      gload16(gA0 + ko, &As[cur ^ 1][wave * 512]);
      gload16(gA1 + ko, &As[cur ^ 1][2048 + wave * 512]);
      gload16(gW0 + ko, &Ws[cur ^ 1][wave * 512]);
      gload16(gW1 + ko, &Ws[cur ^ 1][2048 + wave * 512]);
    }
    bf16x8 af[4], bf[4];
#pragma unroll
    for (int mi = 0; mi < 4; ++mi) {
      int rr = wm + mi * 16 + lr;
      af[mi] =
          *(const bf16x8*)&As[cur][rr * 32 + ((cq ^ ((rr >> 1) & 3)) << 3)];
    }
#pragma unroll
    for (int ni = 0; ni < 4; ++ni) {
      int rr = wn + ni * 16 + lr;
      bf[ni] =
          *(const bf16x8*)&Ws[cur][rr * 32 + ((cq ^ ((rr >> 1) & 3)) << 3)];
    }
#pragma unroll
    for (int mi = 0; mi < 4; ++mi)
#pragma unroll
      for (int ni = 0; ni < 4; ++ni)
        acc[mi][ni] = __builtin_amdgcn_mfma_f32_16x16x32_bf16(
            af[mi], bf[ni], acc[mi][ni], 0, 0, 0);
    __syncthreads();
  }

  int orow = cq << 2, ocol = lr;
#pragma unroll
  for (int mi = 0; mi < 4; ++mi) {
#pragma unroll
    for (int ni = 0; ni < 4; ++ni) {
      int gm = m0 + wm + mi * 16 + orow;
      int gn = n0 + wn + ni * 16 + ocol;
      float bv = (ks == 0) ? bias[gn] : 0.f;
#pragma unroll
      for (int j = 0; j < 4; ++j)
        atomicAdd(&C[(size_t)(gm + j) * ldc + gn], acc[mi][ni][j] + bv);
    }
  }
}

// ---------------- V transpose: qkv V-part -> vt[bh][d][t] ----------------
__global__ __launch_bounds__(256) void vtr_k(const u16* __restrict__ qkv,
                                             u16* __restrict__ vt) {
  __shared__ u16 T[64 * 68];
  int bh = blockIdx.y;
  int b = bh >> 4, h = bh & 15;
  int t0 = blockIdx.x << 6;
  int tid = threadIdx.x;
  int r = tid >> 2, q4 = tid & 3;
  const u16* src = qkv + (size_t)(b * Tm + t0 + r) * 3072 + 2048 + h * 64 +
                   q4 * 16;
  *(u16x8*)&T[r * 68 + q4 * 16] = *(const u16x8*)src;
  *(u16x8*)&T[r * 68 + q4 * 16 + 8] = *(const u16x8*)(src + 8);
  __syncthreads();
  int dr = tid >> 2, kq = tid & 3;
  u16x8 o0, o1;
#pragma unroll
  for (int u = 0; u < 8; ++u) o0[u] = T[(kq * 16 + u) * 68 + dr];
#pragma unroll
  for (int u = 0; u < 8; ++u) o1[u] = T[(kq * 16 + 8 + u) * 68 + dr];
  u16* dst = vt + ((size_t)bh * 64 + dr) * 1024 + t0 + kq * 16;
  *(u16x8*)dst = o0;
  *(u16x8*)(dst + 8) = o1;
}

// ---------------- MFMA flash attention (as r2-r6) ----------------
__global__ __launch_bounds__(256) void attn_k(const u16* __restrict__ qkv,
                                              const u16* __restrict__ vt,
                                              u16* __restrict__ y) {
  __shared__ __align__(16) u16 Ks[2][4096];
  __shared__ __align__(16) u16 Vs[2][4096];
  int qt = gridDim.x - 1 - blockIdx.x;  // big blocks first
  int q0 = qt << 6;
  int bh = blockIdx.y;
  int b = bh >> 4, h = bh & 15;
  int t = threadIdx.x, wave = t >> 6, lane = t & 63;
  int lr = lane & 15, cq = lane >> 4;

  bf16x8 qf[2];
  {
    size_t base = (size_t)(b * Tm + q0 + wave * 16 + lr) * 3072 + h * 64;
#pragma unroll
    for (int ks = 0; ks < 2; ++ks) {
      u16x8 qa = *(const u16x8*)(qkv + base + ks * 32 + cq * 8);
#pragma unroll
      for (int u = 0; u < 8; ++u) qa[u] = f2bf(bf2f(qa[u]) * 0.125f);
      qf[ks] = *(bf16x8*)&qa;
    }
  }

  f32x4 accO[4] = {};
  float m_run = -1e30f, l_run = 0.f;

  int ch0 = wave * 64 + lane, ch1 = 256 + ch0;
  int kr0 = ch0 >> 3, kc0 = ((ch0 & 7) ^ (kr0 & 7)) << 3;
  int kr1 = ch1 >> 3, kc1 = ((ch1 & 7) ^ (kr1 & 7)) << 3;
  const u16* kbase = qkv + (size_t)b * Tm * 3072 + 1024 + h * 64;
  const u16* vbase = vt + (size_t)bh * 64 * 1024;

  {
    gload16(kbase + (size_t)kr0 * 3072 + kc0, &Ks[0][wave * 512]);
    gload16(kbase + (size_t)kr1 * 3072 + kc1, &Ks[0][2048 + wave * 512]);
    gload16(vbase + (size_t)kr0 * 1024 + kc0, &Vs[0][wave * 512]);
    gload16(vbase + (size_t)kr1 * 1024 + kc1, &Vs[0][2048 + wave * 512]);
  }
  __syncthreads();

  for (int tk = 0; tk <= qt; ++tk) {
    int cur = tk & 1;
    if (tk < qt) {
      int kb0 = (tk + 1) << 6;
      gload16(kbase + (size_t)(kb0 + kr0) * 3072 + kc0,
              &Ks[cur ^ 1][wave * 512]);
      gload16(kbase + (size_t)(kb0 + kr1) * 3072 + kc1,
              &Ks[cur ^ 1][2048 + wave * 512]);
      gload16(vbase + (size_t)kr0 * 1024 + kb0 + kc0,
              &Vs[cur ^ 1][wave * 512]);
      gload16(vbase + (size_t)kr1 * 1024 + kb0 + kc1,
              &Vs[cur ^ 1][2048 + wave * 512]);
    }

    f32x4 s[4] = {};
    __builtin_amdgcn_s_setprio(1);
#pragma unroll
    for (int ks = 0; ks < 2; ++ks)
#pragma unroll
      for (int ni = 0; ni < 4; ++ni) {
        int rk = ni * 16 + lr;
        int ck = ks * 4 + cq;
        bf16x8 kf = *(const bf16x8*)&Ks[cur][rk * 64 + ((ck ^ (rk & 7)) << 3)];
        s[ni] = __builtin_amdgcn_mfma_f32_16x16x32_bf16(kf, qf[ks], s[ni],
                                                        0, 0, 0);
      }
    __builtin_amdgcn_s_setprio(0);

    if (tk == qt) {
      int kb0 = tk << 6;
      int qa = q0 + wave * 16 + lr;
#pragma unroll
      for (int ni = 0; ni < 4; ++ni)
#pragma unroll
        for (int r = 0; r < 4; ++r)
          if (kb0 + ni * 16 + cq * 4 + r > qa) s[ni][r] = -1e30f;
    }

    float mx = fmaxf(fmaxf(s[0][0], s[0][1]), fmaxf(s[0][2], s[0][3]));
#pragma unroll
    for (int ni = 1; ni < 4; ++ni)
      mx = fmaxf(mx, fmaxf(fmaxf(s[ni][0], s[ni][1]),
                           fmaxf(s[ni][2], s[ni][3])));
    mx = fmaxf(mx, __shfl_xor(mx, 16));
    mx = fmaxf(mx, __shfl_xor(mx, 32));
    float mn = fmaxf(m_run, mx);
    float alpha = __expf(m_run - mn);
    m_run = mn;
    float ls = 0.f;
    u32 packed[4][2];
#pragma unroll
    for (int ni = 0; ni < 4; ++ni) {
      float p0 = __expf(s[ni][0] - mn), p1 = __expf(s[ni][1] - mn);
      float p2 = __expf(s[ni][2] - mn), p3 = __expf(s[ni][3] - mn);
      ls += (p0 + p1) + (p2 + p3);
      packed[ni][0] = packbf(p0, p1);
      packed[ni][1] = packbf(p2, p3);
    }
    ls += __shfl_xor(ls, 16);
    ls += __shfl_xor(ls, 32);
    l_run = l_run * alpha + ls;

#pragma unroll
    for (int j = 0; j < 4; ++j) {
      float a = __shfl(alpha, (cq << 2) + j);
#pragma unroll
      for (int di = 0; di < 4; ++di) accO[di][j] *= a;
    }

    bf16x8 pf[2];
#pragma unroll
    for (int ks2 = 0; ks2 < 2; ++ks2) {
      union { u32 w[4]; bf16x8 v; } pu;
#pragma unroll
      for (int w = 0; w < 4; ++w) {
        int src = lr + 16 * (((cq & 1) << 1) + (w >> 1));
        int a = __shfl((int)packed[2 * ks2][w & 1], src);
        int bb = __shfl((int)packed[2 * ks2 + 1][w & 1], src);
        pu.w[w] = (cq >> 1) ? (u32)bb : (u32)a;
      }
      pf[ks2] = pu.v;
    }

    __builtin_amdgcn_s_setprio(1);
#pragma unroll
    for (int ks2 = 0; ks2 < 2; ++ks2)
#pragma unroll
      for (int di = 0; di < 4; ++di) {
        int rv = di * 16 + lr;
        int ck = ks2 * 4 + cq;
        bf16x8 vf = *(const bf16x8*)&Vs[cur][rv * 64 + ((ck ^ (rv & 7)) << 3)];
        accO[di] = __builtin_amdgcn_mfma_f32_16x16x32_bf16(pf[ks2], vf,
                                                           accO[di], 0, 0, 0);
      }
    __builtin_amdgcn_s_setprio(0);
    __syncthreads();
  }

  float iv = 1.0f / l_run;
  int qrow = q0 + wave * 16 + (cq << 2);
#pragma unroll
  for (int j = 0; j < 4; ++j) {
    float ivj = __shfl(iv, (cq << 2) + j);
    size_t row = (size_t)(b * Tm + qrow + j) * Dm + h * 64;
#pragma unroll
    for (int di = 0; di < 4; ++di)
      y[row + di * 16 + lr] = f2bf(accO[di][j] * ivj);
  }
}

// ---------------- host ----------------
#define WELEMS ((size_t)(R0 + R1 + R2 + R3))  // 12Mi elems per layer

static inline void launch_gemm(const u16* A, const u16* W, const float* bias,
                               const float* res, float* Cf, u16* Cb, int ldc,
                               int nstore, int K, int gelu, int mblks,
                               int nblks, hipStream_t stream) {
  int gx = 8 * mblks * ((nblks + 7) / 8);
  gemm_k<<<gx, 256, 0, stream>>>(A, W, bias, res, Cf, Cb, ldc, nstore, K,
                                 gelu, mblks, nblks);
}

extern "C" void kernel_launch(void* const* d_in, const int* in_sizes, int n_in,
                              void* d_out, int out_size, void* d_ws,
                              size_t ws_size, hipStream_t stream) {
  const int* idx = (const int*)d_in[0];
  const float* tok = (const float*)d_in[1];
  const float* pos = (const float*)d_in[2];
  const float* ln1w = (const float*)d_in[3];
  const float* ln1b = (const float*)d_in[4];
  const float* qkvw = (const float*)d_in[5];
  const float* qkvb = (const float*)d_in[6];
  const float* projw = (const float*)d_in[7];
  const float* projb = (const float*)d_in[8];
  const float* ln2w = (const float*)d_in[9];
  const float* ln2b = (const float*)d_in[10];
  const float* fc1w = (const float*)d_in[11];
  const float* fc1b = (const float*)d_in[12];
  const float* fc2w = (const float*)d_in[13];
  const float* fc2b = (const float*)d_in[14];
  const float* lnfw = (const float*)d_in[15];
  const float* lnfb = (const float*)d_in[16];
  float* out = (float*)d_out;

  // ws layout
  char* w = (char*)d_ws;
  float* x = (float*)w;  w += (size_t)Mm * Dm * 4;   // 8 MB fp32 residual
  u16* h = (u16*)w;      w += (size_t)Mm * Dm * 2;   // 4 MB LN-out / attn-out
  u16* big = (u16*)w;    w += (size_t)Mm * FFm * 2;  // 16 MB qkv/ff union
  u16* vtG = (u16*)w;    w += (size_t)Bm * 16 * 64 * Tm * 2;  // 4 MB V^T
  u16* wbuf = (u16*)w;   w += WELEMS * 2;            // 24 MB layer weights
  u16* tokbf = (u16*)w;
  size_t need_full = (size_t)(w - (char*)d_ws) + (size_t)VPAD2 * Dm * 2;
  bool full = ws_size >= need_full;

  embed_k<<<Mm, 256, 0, stream>>>(idx, tok, pos, x);

  if (full) {
    long long nsrc = (long long)Vm * Dm, ntot = (long long)VPAD2 * Dm;
    conv_k<<<(int)((ntot + 2047) / 2048), 256, 0, stream>>>(tok, tokbf, nsrc,
                                                            ntot);
  }

  for (int l = 0; l < Lm; ++l) {
    convw_k<<<(int)(WELEMS / 2048), 256, 0, stream>>>(
        qkvw + (size_t)l * R0, projw + (size_t)l * R1, fc1w + (size_t)l * R2,
        fc2w + (size_t)l * R3, wbuf);
    ln_k<<<Mm, 256, 0, stream>>>(x, ln1w + l * Dm, ln1b + l * Dm, h);
    launch_gemm(h, wbuf, qkvb + (size_t)l * 3 * Dm, nullptr, nullptr, big,
                3 * Dm, 3 * Dm, Dm, 0, Mm / 128, (3 * Dm) / 128, stream);
    vtr_k<<<dim3(Tm / 64, Bm * 16), 256, 0, stream>>>(big, vtG);
    attn_k<<<dim3(Tm / 64, Bm * 16), 256, 0, stream>>>(big, vtG, h);
    // proj: split-K=2, atomicAdd into residual x
    gemmsk_k<<<Mm / 128 * (Dm / 128) * 2, 256, 0, stream>>>(
        h, wbuf + R0, projb + (size_t)l * Dm, x, Dm, Dm, Dm / 2, Mm / 128,
        Dm / 128);
    ln_k<<<Mm, 256, 0, stream>>>(x, ln2w + l * Dm, ln2b + l * Dm, h);
    // fc1: 256x256 8-phase
    gemm8_k<<<(Mm / 256) * (FFm / 256), 512, 0, stream>>>(
        h, wbuf + R0 + R1, fc1b + (size_t)l * FFm, nullptr, big, FFm, FFm,
        Dm, 1, Mm / 256, FFm / 256);
    // fc2: split-K=4, atomicAdd into residual x
    gemmsk_k<<<Mm / 128 * (Dm / 128) * 4, 256, 0, stream>>>(
        big, wbuf + R0 + R1 + R2, fc2b + (size_t)l * Dm, x, Dm, FFm, FFm / 4,
        Mm / 128, Dm / 128);
  }

  ln_k<<<Mm, 256, 0, stream>>>(x, lnfw, lnfb, h);

  if (full) {
    gemm8_k<<<(Mm / 256) * (VPAD2 / 256), 512, 0, stream>>>(
        h, tokbf, nullptr, out, nullptr, Vm, Vm, Dm, 0, Mm / 256,
        VPAD2 / 256);
  } else {
    for (int c0 = 0; c0 < VPAD2; c0 += 6400) {
      int rows = VPAD2 - c0 < 6400 ? VPAD2 - c0 : 6400;
      long long nsrc = (long long)(Vm - c0 < rows ? (Vm - c0 > 0 ? Vm - c0 : 0)
                                                  : rows) *
                       Dm;
      long long ntot = (long long)rows * Dm;
      conv_k<<<(int)((ntot + 2047) / 2048), 256, 0, stream>>>(
          tok + (size_t)c0 * Dm, wbuf, nsrc, ntot);
      launch_gemm(h, wbuf, nullptr, nullptr, out + c0, nullptr, Vm, Vm - c0,
                  Dm, 0, Mm / 128, rows / 128, stream);
    }
  }
}

// Round 8
// 1982.091 us; speedup vs baseline: 1.2868x; 1.0937x over previous
//
#include <hip/hip_runtime.h>
#include <cstdint>

#define Dm 1024
#define Tm 1024
#define Bm 2
#define Lm 8
#define FFm 4096
#define Vm 50257
#define Mm (Bm * Tm)
#define VPAD2 50432  // 197*256, zero-padded bf16 tok_emb rows

typedef __bf16 bf16x8 __attribute__((ext_vector_type(8)));
typedef float f32x4 __attribute__((ext_vector_type(4)));
typedef unsigned short u16;
typedef unsigned int u32;
typedef u16 u16x8 __attribute__((ext_vector_type(8)));
typedef u16 u16x4 __attribute__((ext_vector_type(4)));

__device__ __forceinline__ u16 f2bf(float f) {
  u32 u = __float_as_uint(f);
  u += 0x7FFFu + ((u >> 16) & 1u);
  return (u16)(u >> 16);
}
__device__ __forceinline__ float bf2f(u16 u) {
  return __uint_as_float((u32)u << 16);
}
__device__ __forceinline__ u32 packbf(float lo, float hi) {
  return (u32)f2bf(lo) | ((u32)f2bf(hi) << 16);
}

// async global->LDS, 16B per lane. LDS dest: wave-uniform base + lane*16.
__device__ __forceinline__ void gload16(const u16* g, u16* l) {
  __builtin_amdgcn_global_load_lds(
      (const __attribute__((address_space(1))) void*)g,
      (__attribute__((address_space(3))) void*)l, 16, 0, 0);
}

// ---------------- embedding ----------------
__global__ __launch_bounds__(256) void embed_k(
    const int* __restrict__ idx, const float* __restrict__ tok,
    const float* __restrict__ pos, float* __restrict__ x) {
  int m = blockIdx.x, t = threadIdx.x;
  int id = idx[m];
  int tt = m & (Tm - 1);
  float4 a = *(const float4*)(tok + (size_t)id * Dm + t * 4);
  float4 p = *(const float4*)(pos + (size_t)tt * Dm + t * 4);
  float4 o;
  o.x = a.x + p.x; o.y = a.y + p.y; o.z = a.z + p.z; o.w = a.w + p.w;
  *(float4*)(x + (size_t)m * Dm + t * 4) = o;
}

// ---------------- weight conversion fp32 -> bf16 ----------------
__global__ __launch_bounds__(256) void conv_k(const float* __restrict__ s,
                                              u16* __restrict__ d,
                                              long long nsrc, long long ntot) {
  long long i = ((long long)blockIdx.x * 256 + threadIdx.x) * 8;
  if (i >= ntot) return;
  u16x8 r = {0, 0, 0, 0, 0, 0, 0, 0};
  if (i < nsrc) {
    float4 a = *(const float4*)(s + i);
    float4 b = *(const float4*)(s + i + 4);
    r[0] = f2bf(a.x); r[1] = f2bf(a.y); r[2] = f2bf(a.z); r[3] = f2bf(a.w);
    r[4] = f2bf(b.x); r[5] = f2bf(b.y); r[6] = f2bf(b.z); r[7] = f2bf(b.w);
  }
  *(u16x8*)(d + i) = r;
}

#define R0 (3 * Dm * Dm)
#define R1 (Dm * Dm)
#define R2 (FFm * Dm)
#define R3 (Dm * FFm)
__global__ __launch_bounds__(256) void convw_k(
    const float* __restrict__ s0, const float* __restrict__ s1,
    const float* __restrict__ s2, const float* __restrict__ s3,
    u16* __restrict__ d) {
  size_t i = ((size_t)blockIdx.x * 256 + threadIdx.x) * 8;
  const float* s;
  size_t o;
  if (i < R0) { s = s0; o = i; }
  else if (i < (size_t)R0 + R1) { s = s1; o = i - R0; }
  else if (i < (size_t)R0 + R1 + R2) { s = s2; o = i - R0 - R1; }
  else { s = s3; o = i - R0 - R1 - R2; }
  float4 a = *(const float4*)(s + o);
  float4 b = *(const float4*)(s + o + 4);
  u16x8 r;
  r[0] = f2bf(a.x); r[1] = f2bf(a.y); r[2] = f2bf(a.z); r[3] = f2bf(a.w);
  r[4] = f2bf(b.x); r[5] = f2bf(b.y); r[6] = f2bf(b.z); r[7] = f2bf(b.w);
  *(u16x8*)(d + i) = r;
}

// ---------------- layernorm (fp32 in, bf16 out) ----------------
__global__ __launch_bounds__(256) void ln_k(const float* __restrict__ x,
                                            const float* __restrict__ w,
                                            const float* __restrict__ b,
                                            u16* __restrict__ out) {
  __shared__ float red[4];
  int row = blockIdx.x, t = threadIdx.x;
  float4 v = *(const float4*)(x + (size_t)row * Dm + t * 4);
  float s = v.x + v.y + v.z + v.w;
#pragma unroll
  for (int mm = 1; mm < 64; mm <<= 1) s += __shfl_xor(s, mm);
  if ((t & 63) == 0) red[t >> 6] = s;
  __syncthreads();
  float mu = (red[0] + red[1] + red[2] + red[3]) * (1.0f / Dm);
  __syncthreads();
  float dx = v.x - mu, dy = v.y - mu, dz = v.z - mu, dw = v.w - mu;
  float sq = dx * dx + dy * dy + dz * dz + dw * dw;
#pragma unroll
  for (int mm = 1; mm < 64; mm <<= 1) sq += __shfl_xor(sq, mm);
  if ((t & 63) == 0) red[t >> 6] = sq;
  __syncthreads();
  float var = (red[0] + red[1] + red[2] + red[3]) * (1.0f / Dm);
  float rs = rsqrtf(var + 1e-5f);
  float4 wv = *(const float4*)(w + t * 4);
  float4 bv = *(const float4*)(b + t * 4);
  u16x4 o;
  o[0] = f2bf(dx * rs * wv.x + bv.x);
  o[1] = f2bf(dy * rs * wv.y + bv.y);
  o[2] = f2bf(dz * rs * wv.z + bv.z);
  o[3] = f2bf(dw * rs * wv.w + bv.w);
  *(u16x4*)(out + (size_t)row * Dm + t * 4) = o;
}

// ============ gemm8_k: 256x256 tile, 8 waves, m201-faithful schedule =======
// K in 32-chunks cycling 4 LDS slots. Per chunk: 2 phases x 16 MFMA.
// C++ ds_reads (compiler emits fine-grained lgkmcnt), bare-asm counted
// waits (NO memory clobber -- a clobber makes the compiler insert vmcnt(0)
// drains), raw s_barrier, prefetch 3 chunks ahead, graded vmcnt 8/4/0.
__global__ __launch_bounds__(512, 2) void gemm8_k(
    const u16* __restrict__ A, const u16* __restrict__ W,
    const float* __restrict__ bias, float* __restrict__ Cf,
    u16* __restrict__ Cb, int ldc, int nstore, int K, int gelu, int mblks,
    int nblks) {
  __shared__ __align__(16) u16 As[4][8192];
  __shared__ __align__(16) u16 Ws[4][8192];
  int nwg = mblks * nblks;
  int orig = blockIdx.x;
  int q8 = nwg >> 3, r8 = nwg & 7, xcd = orig & 7, loc = orig >> 3;
  int wg = (xcd < r8 ? xcd * (q8 + 1) : r8 * (q8 + 1) + (xcd - r8) * q8) + loc;
  int bx = wg % mblks, by = wg / mblks;
  int m0 = bx << 8, n0 = by << 8;
  int t = threadIdx.x, wave = t >> 6, lane = t & 63;
  int wr = wave >> 2, wc = wave & 3;
  int lr = lane & 15, cq = lane >> 4;
  int sw8 = (cq ^ ((lr >> 1) & 3)) << 3;  // read-side chunk XOR (elements)
  int row0 = t >> 2;
  int kcG = (t & 3) ^ ((t >> 3) & 3);     // source-side XOR (involution)
  const u16* gA = A + (size_t)(m0 + row0) * K + kcG * 8;
  const u16* gW = W + (size_t)(n0 + row0) * K + kcG * 8;
  size_t rstep = (size_t)128 * K;

  f32x4 acc[8][4] = {};
  int nch = K >> 5;

  // prologue: chunks 0..2
  for (int s = 0; s < 3; ++s) {
    gload16(gA + s * 32, &As[s][wave * 512]);
    gload16(gA + rstep + s * 32, &As[s][4096 + wave * 512]);
    gload16(gW + s * 32, &Ws[s][wave * 512]);
    gload16(gW + rstep + s * 32, &Ws[s][4096 + wave * 512]);
  }
  asm volatile("s_waitcnt vmcnt(8)");
  __builtin_amdgcn_s_barrier();

  for (int c = 0; c < nch; ++c) {
    const u16* sA = As[c & 3];
    const u16* sW = Ws[c & 3];
    bf16x8 afA[4], bfr[4], afB[4];
#pragma unroll
    for (int mi = 0; mi < 4; ++mi)
      afA[mi] = *(const bf16x8*)&sA[(wr * 128 + mi * 16 + lr) * 32 + sw8];
#pragma unroll
    for (int ni = 0; ni < 4; ++ni)
      bfr[ni] = *(const bf16x8*)&sW[(wc * 64 + ni * 16 + lr) * 32 + sw8];
#pragma unroll
    for (int mi = 0; mi < 4; ++mi)
      afB[mi] =
          *(const bf16x8*)&sA[(wr * 128 + (mi + 4) * 16 + lr) * 32 + sw8];
    if (c + 3 < nch) {
      int s3 = (c + 3) & 3;
      gload16(gA + (size_t)(c + 3) * 32, &As[s3][wave * 512]);
      gload16(gA + rstep + (size_t)(c + 3) * 32, &As[s3][4096 + wave * 512]);
    }
    __builtin_amdgcn_s_barrier();
    asm volatile("s_waitcnt lgkmcnt(4)");
    __builtin_amdgcn_s_setprio(1);
#pragma unroll
    for (int mi = 0; mi < 4; ++mi)
#pragma unroll
      for (int ni = 0; ni < 4; ++ni)
        acc[mi][ni] = __builtin_amdgcn_mfma_f32_16x16x32_bf16(
            afA[mi], bfr[ni], acc[mi][ni], 0, 0, 0);
    __builtin_amdgcn_s_setprio(0);
    __builtin_amdgcn_s_barrier();
    if (c + 3 < nch) {
      int s3 = (c + 3) & 3;
      gload16(gW + (size_t)(c + 3) * 32, &Ws[s3][wave * 512]);
      gload16(gW + rstep + (size_t)(c + 3) * 32, &Ws[s3][4096 + wave * 512]);
    }
    asm volatile("s_waitcnt lgkmcnt(0)");
    __builtin_amdgcn_s_setprio(1);
#pragma unroll
    for (int mi = 0; mi < 4; ++mi)
#pragma unroll
      for (int ni = 0; ni < 4; ++ni)
        acc[mi + 4][ni] = __builtin_amdgcn_mfma_f32_16x16x32_bf16(
            afB[mi], bfr[ni], acc[mi + 4][ni], 0, 0, 0);
    __builtin_amdgcn_s_setprio(0);
    if (c + 1 < nch) {
      if (c + 3 < nch)
        asm volatile("s_waitcnt vmcnt(8)");
      else if (c + 2 < nch)
        asm volatile("s_waitcnt vmcnt(4)");
      else
        asm volatile("s_waitcnt vmcnt(0)");
    }
    __builtin_amdgcn_s_barrier();
  }

  // epilogue: C/D layout col=lane&15, row=(lane>>4)*4+reg [m89]
  int gm0 = m0 + wr * 128 + (cq << 2);
  int gn0 = n0 + wc * 64 + lr;
#pragma unroll
  for (int mi = 0; mi < 8; ++mi) {
#pragma unroll
    for (int ni = 0; ni < 4; ++ni) {
      int gm = gm0 + mi * 16;
      int gn = gn0 + ni * 16;
      if (gn < nstore) {
        float bv = bias ? bias[gn] : 0.f;
#pragma unroll
        for (int j = 0; j < 4; ++j) {
          float o = acc[mi][ni][j] + bv;
          if (gelu) o = 0.5f * o * (1.0f + erff(o * 0.70710678118654752f));
          if (Cb) Cb[(size_t)(gm + j) * ldc + gn] = f2bf(o);
          else Cf[(size_t)(gm + j) * ldc + gn] = o;
        }
      }
    }
  }
}

// ============ gemm8h_k: 128x256 tile, 8 waves, 1 phase/chunk ==============
// Same schedule, half-height tile -> 2x the blocks (fills the chip for
// fc1/qkv shapes). Per chunk: 8 ds_read + 3 gload + 16 MFMA/wave.
__global__ __launch_bounds__(512, 2) void gemm8h_k(
    const u16* __restrict__ A, const u16* __restrict__ W,
    const float* __restrict__ bias, float* __restrict__ Cf,
    u16* __restrict__ Cb, int ldc, int nstore, int K, int gelu, int mblks,
    int nblks) {
  __shared__ __align__(16) u16 As[4][4096];
  __shared__ __align__(16) u16 Ws[4][8192];
  int nwg = mblks * nblks;
  int orig = blockIdx.x;
  int q8 = nwg >> 3, r8 = nwg & 7, xcd = orig & 7, loc = orig >> 3;
  int wg = (xcd < r8 ? xcd * (q8 + 1) : r8 * (q8 + 1) + (xcd - r8) * q8) + loc;
  int bx = wg % mblks, by = wg / mblks;
  int m0 = bx << 7, n0 = by << 8;
  int t = threadIdx.x, wave = t >> 6, lane = t & 63;
  int wr = wave >> 2, wc = wave & 3;
  int lr = lane & 15, cq = lane >> 4;
  int sw8 = (cq ^ ((lr >> 1) & 3)) << 3;
  int row0 = t >> 2;
  int kcG = (t & 3) ^ ((t >> 3) & 3);
  const u16* gA = A + (size_t)(m0 + row0) * K + kcG * 8;
  const u16* gW = W + (size_t)(n0 + row0) * K + kcG * 8;
  size_t rstep = (size_t)128 * K;

  f32x4 acc[4][4] = {};
  int nch = K >> 5;

  for (int s = 0; s < 3; ++s) {
    gload16(gA + s * 32, &As[s][wave * 512]);
    gload16(gW + s * 32, &Ws[s][wave * 512]);
    gload16(gW + rstep + s * 32, &Ws[s][4096 + wave * 512]);
  }
  asm volatile("s_waitcnt vmcnt(6)");
  __builtin_amdgcn_s_barrier();

  for (int c = 0; c < nch; ++c) {
    const u16* sA = As[c & 3];
    const u16* sW = Ws[c & 3];
    bf16x8 af[4], bf[4];
#pragma unroll
    for (int mi = 0; mi < 4; ++mi)
      af[mi] = *(const bf16x8*)&sA[(wr * 64 + mi * 16 + lr) * 32 + sw8];
#pragma unroll
    for (int ni = 0; ni < 4; ++ni)
      bf[ni] = *(const bf16x8*)&sW[(wc * 64 + ni * 16 + lr) * 32 + sw8];
    if (c + 3 < nch) {
      int s3 = (c + 3) & 3;
      gload16(gA + (size_t)(c + 3) * 32, &As[s3][wave * 512]);
      gload16(gW + (size_t)(c + 3) * 32, &Ws[s3][wave * 512]);
      gload16(gW + rstep + (size_t)(c + 3) * 32, &Ws[s3][4096 + wave * 512]);
    }
    __builtin_amdgcn_s_barrier();
    asm volatile("s_waitcnt lgkmcnt(0)");
    __builtin_amdgcn_s_setprio(1);
#pragma unroll
    for (int mi = 0; mi < 4; ++mi)
#pragma unroll
      for (int ni = 0; ni < 4; ++ni)
        acc[mi][ni] = __builtin_amdgcn_mfma_f32_16x16x32_bf16(
            af[mi], bf[ni], acc[mi][ni], 0, 0, 0);
    __builtin_amdgcn_s_setprio(0);
    if (c + 1 < nch) {
      if (c + 3 < nch)
        asm volatile("s_waitcnt vmcnt(6)");
      else if (c + 2 < nch)
        asm volatile("s_waitcnt vmcnt(3)");
      else
        asm volatile("s_waitcnt vmcnt(0)");
    }
    __builtin_amdgcn_s_barrier();
  }

  int gm0 = m0 + wr * 64 + (cq << 2);
  int gn0 = n0 + wc * 64 + lr;
#pragma unroll
  for (int mi = 0; mi < 4; ++mi) {
#pragma unroll
    for (int ni = 0; ni < 4; ++ni) {
      int gm = gm0 + mi * 16;
      int gn = gn0 + ni * 16;
      if (gn < nstore) {
        float bv = bias ? bias[gn] : 0.f;
#pragma unroll
        for (int j = 0; j < 4; ++j) {
          float o = acc[mi][ni][j] + bv;
          if (gelu) o = 0.5f * o * (1.0f + erff(o * 0.70710678118654752f));
          if (Cb) Cb[(size_t)(gm + j) * ldc + gn] = f2bf(o);
          else Cf[(size_t)(gm + j) * ldc + gn] = o;
        }
      }
    }
  }
}

// ---------------- GEMM 128x128 (fallback logits path) ----------------
__global__ __launch_bounds__(256) void gemm_k(
    const u16* __restrict__ A, const u16* __restrict__ W,
    const float* __restrict__ bias, const float* __restrict__ res,
    float* __restrict__ Cf, u16* __restrict__ Cb, int ldc, int nstore, int K,
    int gelu, int mblks, int nblks) {
  __shared__ __align__(16) u16 As[2][4096];
  __shared__ __align__(16) u16 Ws[2][4096];
  int id = blockIdx.x;
  int c = id & 7, m2 = id >> 3;
  int bx = m2 % mblks;
  int by = (m2 / mblks) * 8 + c;
  if (by >= nblks) return;
  int m0 = bx << 7, n0 = by << 7;
  int t = threadIdx.x;
  int wave = t >> 6, lane = t & 63;
  int wm = (wave & 1) << 6, wn = (wave >> 1) << 6;
  int lr = lane & 15, cq = lane >> 4;

  f32x4 acc[4][4] = {};

  int ch0 = wave * 64 + lane;
  int ch1 = 256 + ch0;
  int r0 = ch0 >> 2, c0 = (ch0 & 3) ^ ((r0 >> 1) & 3);
  int r1 = ch1 >> 2, c1 = (ch1 & 3) ^ ((r1 >> 1) & 3);
  const u16* gA0 = A + (size_t)(m0 + r0) * K + c0 * 8;
  const u16* gA1 = A + (size_t)(m0 + r1) * K + c1 * 8;
  const u16* gW0 = W + (size_t)(n0 + r0) * K + c0 * 8;
  const u16* gW1 = W + (size_t)(n0 + r1) * K + c1 * 8;

  int nst = K >> 5;
  gload16(gA0, &As[0][wave * 512]);
  gload16(gA1, &As[0][2048 + wave * 512]);
  gload16(gW0, &Ws[0][wave * 512]);
  gload16(gW1, &Ws[0][2048 + wave * 512]);
  __syncthreads();

  for (int i = 0; i < nst; ++i) {
    int cur = i & 1;
    if (i + 1 < nst) {
      int ko = (i + 1) << 5;
      gload16(gA0 + ko, &As[cur ^ 1][wave * 512]);
      gload16(gA1 + ko, &As[cur ^ 1][2048 + wave * 512]);
      gload16(gW0 + ko, &Ws[cur ^ 1][wave * 512]);
      gload16(gW1 + ko, &Ws[cur ^ 1][2048 + wave * 512]);
    }
    bf16x8 af[4], bf[4];
#pragma unroll
    for (int mi = 0; mi < 4; ++mi) {
      int rr = wm + mi * 16 + lr;
      af[mi] =
          *(const bf16x8*)&As[cur][rr * 32 + ((cq ^ ((rr >> 1) & 3)) << 3)];
    }
#pragma unroll
    for (int ni = 0; ni < 4; ++ni) {
      int rr = wn + ni * 16 + lr;
      bf[ni] =
          *(const bf16x8*)&Ws[cur][rr * 32 + ((cq ^ ((rr >> 1) & 3)) << 3)];
    }
#pragma unroll
    for (int mi = 0; mi < 4; ++mi)
#pragma unroll
      for (int ni = 0; ni < 4; ++ni)
        acc[mi][ni] = __builtin_amdgcn_mfma_f32_16x16x32_bf16(
            af[mi], bf[ni], acc[mi][ni], 0, 0, 0);
    __syncthreads();
  }

  int orow = cq << 2, ocol = lr;
#pragma unroll
  for (int mi = 0; mi < 4; ++mi) {
#pragma unroll
    for (int ni = 0; ni < 4; ++ni) {
      int gm = m0 + wm + mi * 16 + orow;
      int gn = n0 + wn + ni * 16 + ocol;
      if (gn < nstore) {
        float bv = bias ? bias[gn] : 0.f;
#pragma unroll
        for (int j = 0; j < 4; ++j) {
          float o = acc[mi][ni][j] + bv;
          if (gelu) o = 0.5f * o * (1.0f + erff(o * 0.70710678118654752f));
          if (res) o += res[(size_t)(gm + j) * ldc + gn];
          if (Cb) Cb[(size_t)(gm + j) * ldc + gn] = f2bf(o);
          else Cf[(size_t)(gm + j) * ldc + gn] = o;
        }
      }
    }
  }
}

// ---------------- split-K GEMM 128x128, atomicAdd epilogue ----------------
__global__ __launch_bounds__(256) void gemmsk_k(
    const u16* __restrict__ A, const u16* __restrict__ W,
    const float* __restrict__ bias, float* __restrict__ C, int ldc, int K,
    int klen, int mblks, int nblks) {
  __shared__ __align__(16) u16 As[2][4096];
  __shared__ __align__(16) u16 Ws[2][4096];
  int id = blockIdx.x;
  int bx = id % mblks;
  int tmp = id / mblks;
  int by = tmp % nblks;
  int ks = tmp / nblks;
  int m0 = bx << 7, n0 = by << 7;
  int koff = ks * klen;
  int t = threadIdx.x;
  int wave = t >> 6, lane = t & 63;
  int wm = (wave & 1) << 6, wn = (wave >> 1) << 6;
  int lr = lane & 15, cq = lane >> 4;

  f32x4 acc[4][4] = {};

  int ch0 = wave * 64 + lane;
  int ch1 = 256 + ch0;
  int r0 = ch0 >> 2, c0 = (ch0 & 3) ^ ((r0 >> 1) & 3);
  int r1 = ch1 >> 2, c1 = (ch1 & 3) ^ ((r1 >> 1) & 3);
  const u16* gA0 = A + (size_t)(m0 + r0) * K + koff + c0 * 8;
  const u16* gA1 = A + (size_t)(m0 + r1) * K + koff + c1 * 8;
  const u16* gW0 = W + (size_t)(n0 + r0) * K + koff + c0 * 8;
  const u16* gW1 = W + (size_t)(n0 + r1) * K + koff + c1 * 8;

  int nst = klen >> 5;
  gload16(gA0, &As[0][wave * 512]);
  gload16(gA1, &As[0][2048 + wave * 512]);
  gload16(gW0, &Ws[0][wave * 512]);
  gload16(gW1, &Ws[0][2048 + wave * 512]);
  __syncthreads();

  for (int i = 0; i < nst; ++i) {
    int cur = i & 1;
    if (i + 1 < nst) {
      int ko = (i + 1) << 5;
      gload16(gA0 + ko, &As[cur ^ 1][wave * 512]);
      gload16(gA1 + ko, &As[cur ^ 1][2048 + wave * 512]);
      gload16(gW0 + ko, &Ws[cur ^ 1][wave * 512]);
      gload16(gW1 + ko, &Ws[cur ^ 1][2048 + wave * 512]);
    }
    bf16x8 af[4], bf[4];
#pragma unroll
    for (int mi = 0; mi < 4; ++mi) {
      int rr = wm + mi * 16 + lr;
      af[mi] =
          *(const bf16x8*)&As[cur][rr * 32 + ((cq ^ ((rr >> 1) & 3)) << 3)];
    }
#pragma unroll
    for (int ni = 0; ni < 4; ++ni) {
      int rr = wn + ni * 16 + lr;
      bf[ni] =
          *(const bf16x8*)&Ws[cur][rr * 32 + ((cq ^ ((rr >> 1) & 3)) << 3)];
    }
#pragma unroll
    for (int mi = 0; mi < 4; ++mi)
#pragma unroll
      for (int ni = 0; ni < 4; ++ni)
        acc[mi][ni] = __builtin_amdgcn_mfma_f32_16x16x32_bf16(
            af[mi], bf[ni], acc[mi][ni], 0, 0, 0);
    __syncthreads();
  }

  int orow = cq << 2, ocol = lr;
#pragma unroll
  for (int mi = 0; mi < 4; ++mi) {
#pragma unroll
    for (int ni = 0; ni < 4; ++ni) {
      int gm = m0 + wm + mi * 16 + orow;
      int gn = n0 + wn + ni * 16 + ocol;
      float bv = (ks == 0) ? bias[gn] : 0.f;
#pragma unroll
      for (int j = 0; j < 4; ++j)
        atomicAdd(&C[(size_t)(gm + j) * ldc + gn], acc[mi][ni][j] + bv);
    }
  }
}

// ---------------- V transpose: qkv V-part -> vt[bh][d][t] ----------------
__global__ __launch_bounds__(256) void vtr_k(const u16* __restrict__ qkv,
                                             u16* __restrict__ vt) {
  __shared__ u16 T[64 * 68];
  int bh = blockIdx.y;
  int b = bh >> 4, h = bh & 15;
  int t0 = blockIdx.x << 6;
  int tid = threadIdx.x;
  int r = tid >> 2, q4 = tid & 3;
  const u16* src = qkv + (size_t)(b * Tm + t0 + r) * 3072 + 2048 + h * 64 +
                   q4 * 16;
  *(u16x8*)&T[r * 68 + q4 * 16] = *(const u16x8*)src;
  *(u16x8*)&T[r * 68 + q4 * 16 + 8] = *(const u16x8*)(src + 8);
  __syncthreads();
  int dr = tid >> 2, kq = tid & 3;
  u16x8 o0, o1;
#pragma unroll
  for (int u = 0; u < 8; ++u) o0[u] = T[(kq * 16 + u) * 68 + dr];
#pragma unroll
  for (int u = 0; u < 8; ++u) o1[u] = T[(kq * 16 + 8 + u) * 68 + dr];
  u16* dst = vt + ((size_t)bh * 64 + dr) * 1024 + t0 + kq * 16;
  *(u16x8*)dst = o0;
  *(u16x8*)(dst + 8) = o1;
}

// ---------------- MFMA flash attention (as r2-r7) ----------------
__global__ __launch_bounds__(256) void attn_k(const u16* __restrict__ qkv,
                                              const u16* __restrict__ vt,
                                              u16* __restrict__ y) {
  __shared__ __align__(16) u16 Ks[2][4096];
  __shared__ __align__(16) u16 Vs[2][4096];
  int qt = gridDim.x - 1 - blockIdx.x;  // big blocks first
  int q0 = qt << 6;
  int bh = blockIdx.y;
  int b = bh >> 4, h = bh & 15;
  int t = threadIdx.x, wave = t >> 6, lane = t & 63;
  int lr = lane & 15, cq = lane >> 4;

  bf16x8 qf[2];
  {
    size_t base = (size_t)(b * Tm + q0 + wave * 16 + lr) * 3072 + h * 64;
#pragma unroll
    for (int ks = 0; ks < 2; ++ks) {
      u16x8 qa = *(const u16x8*)(qkv + base + ks * 32 + cq * 8);
#pragma unroll
      for (int u = 0; u < 8; ++u) qa[u] = f2bf(bf2f(qa[u]) * 0.125f);
      qf[ks] = *(bf16x8*)&qa;
    }
  }

  f32x4 accO[4] = {};
  float m_run = -1e30f, l_run = 0.f;

  int ch0 = wave * 64 + lane, ch1 = 256 + ch0;
  int kr0 = ch0 >> 3, kc0 = ((ch0 & 7) ^ (kr0 & 7)) << 3;
  int kr1 = ch1 >> 3, kc1 = ((ch1 & 7) ^ (kr1 & 7)) << 3;
  const u16* kbase = qkv + (size_t)b * Tm * 3072 + 1024 + h * 64;
  const u16* vbase = vt + (size_t)bh * 64 * 1024;

  {
    gload16(kbase + (size_t)kr0 * 3072 + kc0, &Ks[0][wave * 512]);
    gload16(kbase + (size_t)kr1 * 3072 + kc1, &Ks[0][2048 + wave * 512]);
    gload16(vbase + (size_t)kr0 * 1024 + kc0, &Vs[0][wave * 512]);
    gload16(vbase + (size_t)kr1 * 1024 + kc1, &Vs[0][2048 + wave * 512]);
  }
  __syncthreads();

  for (int tk = 0; tk <= qt; ++tk) {
    int cur = tk & 1;
    if (tk < qt) {
      int kb0 = (tk + 1) << 6;
      gload16(kbase + (size_t)(kb0 + kr0) * 3072 + kc0,
              &Ks[cur ^ 1][wave * 512]);
      gload16(kbase + (size_t)(kb0 + kr1) * 3072 + kc1,
              &Ks[cur ^ 1][2048 + wave * 512]);
      gload16(vbase + (size_t)kr0 * 1024 + kb0 + kc0,
              &Vs[cur ^ 1][wave * 512]);
      gload16(vbase + (size_t)kr1 * 1024 + kb0 + kc1,
              &Vs[cur ^ 1][2048 + wave * 512]);
    }

    f32x4 s[4] = {};
    __builtin_amdgcn_s_setprio(1);
#pragma unroll
    for (int ks = 0; ks < 2; ++ks)
#pragma unroll
      for (int ni = 0; ni < 4; ++ni) {
        int rk = ni * 16 + lr;
        int ck = ks * 4 + cq;
        bf16x8 kf = *(const bf16x8*)&Ks[cur][rk * 64 + ((ck ^ (rk & 7)) << 3)];
        s[ni] = __builtin_amdgcn_mfma_f32_16x16x32_bf16(kf, qf[ks], s[ni],
                                                        0, 0, 0);
      }
    __builtin_amdgcn_s_setprio(0);

    if (tk == qt) {
      int kb0 = tk << 6;
      int qa = q0 + wave * 16 + lr;
#pragma unroll
      for (int ni = 0; ni < 4; ++ni)
#pragma unroll
        for (int r = 0; r < 4; ++r)
          if (kb0 + ni * 16 + cq * 4 + r > qa) s[ni][r] = -1e30f;
    }

    float mx = fmaxf(fmaxf(s[0][0], s[0][1]), fmaxf(s[0][2], s[0][3]));
#pragma unroll
    for (int ni = 1; ni < 4; ++ni)
      mx = fmaxf(mx, fmaxf(fmaxf(s[ni][0], s[ni][1]),
                           fmaxf(s[ni][2], s[ni][3])));
    mx = fmaxf(mx, __shfl_xor(mx, 16));
    mx = fmaxf(mx, __shfl_xor(mx, 32));
    float mn = fmaxf(m_run, mx);
    float alpha = __expf(m_run - mn);
    m_run = mn;
    float ls = 0.f;
    u32 packed[4][2];
#pragma unroll
    for (int ni = 0; ni < 4; ++ni) {
      float p0 = __expf(s[ni][0] - mn), p1 = __expf(s[ni][1] - mn);
      float p2 = __expf(s[ni][2] - mn), p3 = __expf(s[ni][3] - mn);
      ls += (p0 + p1) + (p2 + p3);
      packed[ni][0] = packbf(p0, p1);
      packed[ni][1] = packbf(p2, p3);
    }
    ls += __shfl_xor(ls, 16);
    ls += __shfl_xor(ls, 32);
    l_run = l_run * alpha + ls;

#pragma unroll
    for (int j = 0; j < 4; ++j) {
      float a = __shfl(alpha, (cq << 2) + j);
#pragma unroll
      for (int di = 0; di < 4; ++di) accO[di][j] *= a;
    }

    bf16x8 pf[2];
#pragma unroll
    for (int ks2 = 0; ks2 < 2; ++ks2) {
      union { u32 w[4]; bf16x8 v; } pu;
#pragma unroll
      for (int w = 0; w < 4; ++w) {
        int src = lr + 16 * (((cq & 1) << 1) + (w >> 1));
        int a = __shfl((int)packed[2 * ks2][w & 1], src);
        int bb = __shfl((int)packed[2 * ks2 + 1][w & 1], src);
        pu.w[w] = (cq >> 1) ? (u32)bb : (u32)a;
      }
      pf[ks2] = pu.v;
    }

    __builtin_amdgcn_s_setprio(1);
#pragma unroll
    for (int ks2 = 0; ks2 < 2; ++ks2)
#pragma unroll
      for (int di = 0; di < 4; ++di) {
        int rv = di * 16 + lr;
        int ck = ks2 * 4 + cq;
        bf16x8 vf = *(const bf16x8*)&Vs[cur][rv * 64 + ((ck ^ (rv & 7)) << 3)];
        accO[di] = __builtin_amdgcn_mfma_f32_16x16x32_bf16(pf[ks2], vf,
                                                           accO[di], 0, 0, 0);
      }
    __builtin_amdgcn_s_setprio(0);
    __syncthreads();
  }

  float iv = 1.0f / l_run;
  int qrow = q0 + wave * 16 + (cq << 2);
#pragma unroll
  for (int j = 0; j < 4; ++j) {
    float ivj = __shfl(iv, (cq << 2) + j);
    size_t row = (size_t)(b * Tm + qrow + j) * Dm + h * 64;
#pragma unroll
    for (int di = 0; di < 4; ++di)
      y[row + di * 16 + lr] = f2bf(accO[di][j] * ivj);
  }
}

// ---------------- host ----------------
#define WELEMS ((size_t)(R0 + R1 + R2 + R3))  // 12Mi elems per layer

static inline void launch_gemm(const u16* A, const u16* W, const float* bias,
                               const float* res, float* Cf, u16* Cb, int ldc,
                               int nstore, int K, int gelu, int mblks,
                               int nblks, hipStream_t stream) {
  int gx = 8 * mblks * ((nblks + 7) / 8);
  gemm_k<<<gx, 256, 0, stream>>>(A, W, bias, res, Cf, Cb, ldc, nstore, K,
                                 gelu, mblks, nblks);
}

extern "C" void kernel_launch(void* const* d_in, const int* in_sizes, int n_in,
                              void* d_out, int out_size, void* d_ws,
                              size_t ws_size, hipStream_t stream) {
  const int* idx = (const int*)d_in[0];
  const float* tok = (const float*)d_in[1];
  const float* pos = (const float*)d_in[2];
  const float* ln1w = (const float*)d_in[3];
  const float* ln1b = (const float*)d_in[4];
  const float* qkvw = (const float*)d_in[5];
  const float* qkvb = (const float*)d_in[6];
  const float* projw = (const float*)d_in[7];
  const float* projb = (const float*)d_in[8];
  const float* ln2w = (const float*)d_in[9];
  const float* ln2b = (const float*)d_in[10];
  const float* fc1w = (const float*)d_in[11];
  const float* fc1b = (const float*)d_in[12];
  const float* fc2w = (const float*)d_in[13];
  const float* fc2b = (const float*)d_in[14];
  const float* lnfw = (const float*)d_in[15];
  const float* lnfb = (const float*)d_in[16];
  float* out = (float*)d_out;

  // ws layout
  char* w = (char*)d_ws;
  float* x = (float*)w;  w += (size_t)Mm * Dm * 4;   // 8 MB fp32 residual
  u16* h = (u16*)w;      w += (size_t)Mm * Dm * 2;   // 4 MB LN-out / attn-out
  u16* big = (u16*)w;    w += (size_t)Mm * FFm * 2;  // 16 MB qkv/ff union
  u16* vtG = (u16*)w;    w += (size_t)Bm * 16 * 64 * Tm * 2;  // 4 MB V^T
  u16* wbuf = (u16*)w;   w += WELEMS * 2;            // 24 MB layer weights
  u16* tokbf = (u16*)w;
  size_t need_full = (size_t)(w - (char*)d_ws) + (size_t)VPAD2 * Dm * 2;
  bool full = ws_size >= need_full;

  embed_k<<<Mm, 256, 0, stream>>>(idx, tok, pos, x);

  if (full) {
    long long nsrc = (long long)Vm * Dm, ntot = (long long)VPAD2 * Dm;
    conv_k<<<(int)((ntot + 2047) / 2048), 256, 0, stream>>>(tok, tokbf, nsrc,
                                                            ntot);
  }

  for (int l = 0; l < Lm; ++l) {
    convw_k<<<(int)(WELEMS / 2048), 256, 0, stream>>>(
        qkvw + (size_t)l * R0, projw + (size_t)l * R1, fc1w + (size_t)l * R2,
        fc2w + (size_t)l * R3, wbuf);
    ln_k<<<Mm, 256, 0, stream>>>(x, ln1w + l * Dm, ln1b + l * Dm, h);
    // qkv: 128x256 8-phase (192 blocks)
    gemm8h_k<<<(Mm / 128) * ((3 * Dm) / 256), 512, 0, stream>>>(
        h, wbuf, qkvb + (size_t)l * 3 * Dm, nullptr, big, 3 * Dm, 3 * Dm, Dm,
        0, Mm / 128, (3 * Dm) / 256);
    vtr_k<<<dim3(Tm / 64, Bm * 16), 256, 0, stream>>>(big, vtG);
    attn_k<<<dim3(Tm / 64, Bm * 16), 256, 0, stream>>>(big, vtG, h);
    // proj: split-K=2, atomicAdd into residual x
    gemmsk_k<<<Mm / 128 * (Dm / 128) * 2, 256, 0, stream>>>(
        h, wbuf + R0, projb + (size_t)l * Dm, x, Dm, Dm, Dm / 2, Mm / 128,
        Dm / 128);
    ln_k<<<Mm, 256, 0, stream>>>(x, ln2w + l * Dm, ln2b + l * Dm, h);
    // fc1: 128x256 8-phase (256 blocks)
    gemm8h_k<<<(Mm / 128) * (FFm / 256), 512, 0, stream>>>(
        h, wbuf + R0 + R1, fc1b + (size_t)l * FFm, nullptr, big, FFm, FFm,
        Dm, 1, Mm / 128, FFm / 256);
    // fc2: split-K=4, atomicAdd into residual x
    gemmsk_k<<<Mm / 128 * (Dm / 128) * 4, 256, 0, stream>>>(
        big, wbuf + R0 + R1 + R2, fc2b + (size_t)l * Dm, x, Dm, FFm, FFm / 4,
        Mm / 128, Dm / 128);
  }

  ln_k<<<Mm, 256, 0, stream>>>(x, lnfw, lnfb, h);

  if (full) {
    gemm8_k<<<(Mm / 256) * (VPAD2 / 256), 512, 0, stream>>>(
        h, tokbf, nullptr, out, nullptr, Vm, Vm, Dm, 0, Mm / 256,
        VPAD2 / 256);
  } else {
    for (int c0 = 0; c0 < VPAD2; c0 += 6400) {
      int rows = VPAD2 - c0 < 6400 ? VPAD2 - c0 : 6400;
      long long nsrc = (long long)(Vm - c0 < rows ? (Vm - c0 > 0 ? Vm - c0 : 0)
                                                  : rows) *
                       Dm;
      long long ntot = (long long)rows * Dm;
      conv_k<<<(int)((ntot + 2047) / 2048), 256, 0, stream>>>(
          tok + (size_t)c0 * Dm, wbuf, nsrc, ntot);
      launch_gemm(h, wbuf, nullptr, nullptr, out + c0, nullptr, Vm, Vm - c0,
                  Dm, 0, Mm / 128, rows / 128, stream);
    }
  }
}